// Round 2
// baseline (3285.679 us; speedup 1.0000x reference)
//
#include <hip/hip_runtime.h>
#include <hip/hip_bf16.h>

#define NN 10000
#define NE 160000
#define NZ 10
#define NC 64
#define NBES 8
#define NG 16
#define NT 2

static constexpr float PI_F  = 3.14159265358979323846f;
static constexpr float KBES  = 0.63245553203367587f;  // sqrt(2/5)
static constexpr float S3    = 1.73205080756887729f;
static constexpr float S5    = 2.23606797749978969f;
static constexpr float S15   = 3.87298334620741688f;

// ---- workspace layout (float offsets) ----
static constexpr size_t OFF_SH   = 0;
static constexpr size_t OFF_EF   = OFF_SH  + (size_t)NE*9;
static constexpr size_t OFF_RL   = OFF_EF  + (size_t)NE*8;
static constexpr size_t OFF_UV   = OFF_RL  + (size_t)NE;
static constexpr size_t OFF_PIN  = OFF_UV  + (size_t)NE*3;   // positions f32
static constexpr size_t OFF_ATT  = OFF_PIN + (size_t)NN*3;   // node_attrs f32
static constexpr size_t OFF_CHG  = OFF_ATT + (size_t)NN*NZ;  // charges f32
static constexpr size_t OFF_SHF  = OFF_CHG + (size_t)NN;     // shifts f32
static constexpr size_t NFSZ     = (size_t)NN*576;
static constexpr size_t OFF_NF0  = OFF_SHF + (size_t)NE*3;
static constexpr size_t OFF_NF1  = OFF_NF0 + NFSZ;
static constexpr size_t OFF_NF2  = OFF_NF1 + NFSZ;   // aliased as gnf "A" in bwd
static constexpr size_t OFF_MSG0 = OFF_NF2 + NFSZ;
static constexpr size_t OFF_MSG1 = OFF_MSG0+ NFSZ;   // aliased as gnf "B" in bwd
static constexpr size_t OFF_AGG  = OFF_MSG1+ NFSZ;   // agg / mp / gmp / gmsg scratch
static constexpr size_t OFF_W    = OFF_AGG + NFSZ;
static constexpr size_t O_WEMB   = OFF_W;
static constexpr size_t O_AE     = O_WEMB + 640;
static constexpr size_t O_R1     = O_AE   + 16;
static constexpr size_t O_R2     = O_R1   + 1024;
static constexpr size_t O_R2T    = O_R2   + 8192;
static constexpr size_t O_WMIX   = O_R2T  + 8192;
static constexpr size_t O_WMIXT  = O_WMIX + 24576;
static constexpr size_t O_WSC    = O_WMIXT+ 24576;
static constexpr size_t O_WSCT   = O_WSC  + 24576;
static constexpr size_t O_WPROD  = O_WSCT + 24576;
static constexpr size_t O_WPRODT = O_WPROD+ 24576;
static constexpr size_t O_WPOLY  = O_WPRODT+24576;
static constexpr size_t O_WE     = O_WPOLY+ 384;
static constexpr size_t O_WD     = O_WE   + 128;
static constexpr size_t OFF_ACC  = O_WD   + 128;
static constexpr size_t O_E0G    = OFF_ACC;          // 16
static constexpr size_t O_ETG    = O_E0G + 16;       // 32 ([t][g])
static constexpr size_t O_TD     = O_ETG + 32;       // 48
static constexpr size_t O_ADP    = O_TD  + 48;       // N*3
static constexpr size_t O_GPOS   = O_ADP + (size_t)NN*3;
static constexpr size_t O_FLAG   = O_GPOS+ (size_t)NN*3;     // dtype flag (int)
static constexpr size_t WS_FLOATS= O_FLAG + 4;
static constexpr size_t ACC_FLOATS = WS_FLOATS - OFF_ACC;

// ---------- dtype detection: node_attrs is one-hot {0,1} ----------
// fp32 words are only 0x00000000 / 0x3F800000. Packed-bf16 pairs also produce
// 0x00003F80 (1.0 at even index) or 0x3F803F80 — unambiguous bf16 markers.
__global__ void k_detect(const unsigned* __restrict__ raw, int* __restrict__ flag){
  __shared__ int found;
  if (threadIdx.x == 0) found = 0;
  __syncthreads();
  for (int i = threadIdx.x; i < 4096; i += 256){
    unsigned w = raw[i];
    if (w == 0x00003F80u || w == 0x3F803F80u) found = 1;
  }
  __syncthreads();
  if (threadIdx.x == 0) flag[0] = found;
}

// ---------- generic loader: src (bf16 or f32 per flag) -> f32 ----------
__global__ void k_load(const void* __restrict__ src, float* __restrict__ dst, int n,
                       const int* __restrict__ flag){
  int i = blockIdx.x*256 + threadIdx.x;
  if (i >= n) return;
  if (flag[0]) dst[i] = __bfloat162float(((const __hip_bfloat16*)src)[i]);
  else         dst[i] = ((const float*)src)[i];
}

// transpose m 64x64 matrices
__global__ void k_transpose64(const float* __restrict__ s, float* __restrict__ d, int m){
  int i = blockIdx.x*256 + threadIdx.x;
  if (i >= m*4096) return;
  int mm = i >> 12, r = (i >> 6) & 63, c = i & 63;
  d[(size_t)mm*4096 + (size_t)c*64 + r] = s[(size_t)mm*4096 + (size_t)r*64 + c];
}

// ---------- edge geometry: sh, radial embed, r, u ----------
__global__ void k_geom(const float* __restrict__ pos, const float* __restrict__ shifts,
                       const int* __restrict__ ei, float* __restrict__ sh, float* __restrict__ ef,
                       float* __restrict__ rl, float* __restrict__ uv){
  int e = blockIdx.x*256 + threadIdx.x;
  if (e >= NE) return;
  int s = ei[e], r = ei[NE + e];
  float vx = pos[s*3+0] - pos[r*3+0] + shifts[(size_t)e*3+0];
  float vy = pos[s*3+1] - pos[r*3+1] + shifts[(size_t)e*3+1];
  float vz = pos[s*3+2] - pos[r*3+2] + shifts[(size_t)e*3+2];
  float L = sqrtf(vx*vx + vy*vy + vz*vz + 1e-12f);
  float inv = 1.f / L;
  float x = vx*inv, y = vy*inv, z = vz*inv;
  float* shp = sh + (size_t)e*9;
  shp[0] = 1.f;     shp[1] = S3*x;    shp[2] = S3*y;   shp[3] = S3*z;
  shp[4] = S15*x*y; shp[5] = S15*y*z; shp[6] = 0.5f*S5*(3.f*z*z - 1.f);
  shp[7] = S15*x*z; shp[8] = 0.5f*S15*(x*x - y*y);
  rl[e] = L;
  uv[(size_t)e*3+0] = x; uv[(size_t)e*3+1] = y; uv[(size_t)e*3+2] = z;
  float ur = L * 0.2f;
  float fc = 0.f;
  if (ur < 1.f){
    float u2 = ur*ur, u4 = u2*u2, u5 = u4*ur;
    fc = 1.f - 21.f*u5 + 35.f*u5*ur - 15.f*u5*u2;
  }
  float invr = 1.f / (L + 1e-9f);
  float* efp = ef + (size_t)e*8;
  #pragma unroll
  for (int b = 0; b < 8; ++b){
    float arg = (float)(b+1) * PI_F * ur;
    efp[b] = KBES * sinf(arg) * invr * fc;
  }
}

// ---------- node init: embedding + e0 ----------
__global__ void k_init_nodes(const float* __restrict__ attrs, const float* __restrict__ Wemb,
                             const float* __restrict__ ae, const int* __restrict__ batch,
                             float* __restrict__ nf0, float* __restrict__ e0g){
  int n = blockIdx.x, c = threadIdx.x;
  float acc = 0.f;
  #pragma unroll
  for (int z = 0; z < NZ; ++z) acc = fmaf(attrs[(size_t)n*NZ+z], Wemb[z*64+c], acc);
  size_t base = (size_t)n*576;
  nf0[base + c] = acc;
  #pragma unroll
  for (int k = 1; k < 9; ++k) nf0[base + (size_t)k*64 + c] = 0.f;
  if (c == 0){
    float e = 0.f;
    #pragma unroll
    for (int z = 0; z < NZ; ++z) e = fmaf(attrs[(size_t)n*NZ+z], ae[z], e);
    atomicAdd(&e0g[batch[n]], e);
  }
}

// ---------- forward edge kernel: radial MLP + message scatter ----------
__global__ __launch_bounds__(256) void k_edge_fwd(
    const float* __restrict__ ef, const float* __restrict__ sh, const float* __restrict__ nfprev,
    const int* __restrict__ ei, const float* __restrict__ R1, const float* __restrict__ R2,
    float* __restrict__ agg){
  __shared__ float R1s[512];
  __shared__ float R2s[4096];
  __shared__ float sa[4][64];
  for (int i = threadIdx.x; i < 512;  i += 256) R1s[i] = R1[i];
  for (int i = threadIdx.x; i < 4096; i += 256) R2s[i] = R2[i];
  __syncthreads();
  int lane = threadIdx.x & 63, wv = threadIdx.x >> 6;
  int ebase = blockIdx.x*32 + wv*8;
  for (int it = 0; it < 8; ++it){
    int e = ebase + it;
    const float* efp = ef + (size_t)e*8;
    float a = 0.f;
    #pragma unroll
    for (int b = 0; b < 8; ++b) a = fmaf(efp[b], R1s[b*64+lane], a);
    float sg = 1.f/(1.f + __expf(-a));
    sa[wv][lane] = a*sg;
    __syncthreads();
    float w = 0.f;
    #pragma unroll
    for (int j = 0; j < 64; ++j) w = fmaf(sa[wv][j], R2s[j*64+lane], w);
    __syncthreads();
    int s = ei[e], r = ei[NE + e];
    float h = nfprev[(size_t)s*576 + lane];
    float base = w*h*(1.f/16.f);
    const float* shp = sh + (size_t)e*9;
    float* ap = agg + (size_t)r*576 + lane;
    #pragma unroll
    for (int k = 0; k < 9; ++k) atomicAdd(ap + (size_t)k*64, base*shp[k]);
  }
}

// ---------- per-l linear: out[n,k,d] = sum_c in[n,k,c]*W[l(k)][c,d] ----------
__global__ __launch_bounds__(256) void k_lin(const float* __restrict__ in, const float* __restrict__ W3,
                                             float* __restrict__ out, int accum){
  __shared__ float Wl[4096];
  int k = blockIdx.y;
  int l = (k==0) ? 0 : ((k<4) ? 1 : 2);
  const float* W = W3 + (size_t)l*4096;
  for (int i = threadIdx.x; i < 4096; i += 256) Wl[i] = W[i];
  __syncthreads();
  int d = threadIdx.x & 63, sub = threadIdx.x >> 6;
  int nbase = blockIdx.x*16;
  for (int i = 0; i < 4; ++i){
    int n = nbase + sub*4 + i;
    const float* inr = in + (size_t)n*576 + (size_t)k*64;
    float acc = 0.f;
    #pragma unroll
    for (int c = 0; c < 64; ++c) acc = fmaf(inr[c], Wl[c*64+d], acc);
    float* o = out + (size_t)n*576 + (size_t)k*64 + d;
    if (accum) *o += acc; else *o = acc;
  }
}

// ---------- poly gate forward: mp = msg * poly(s0) ----------
__global__ void k_poly(const float* __restrict__ msg, const float* __restrict__ wp, float* __restrict__ mp){
  int n = blockIdx.x, c = threadIdx.x;
  size_t base = (size_t)n*576 + c;
  float s0 = msg[base];
  float p = fmaf(fmaf(wp[c*3+2], s0, wp[c*3+1]), s0, wp[c*3+0]);
  #pragma unroll
  for (int k = 0; k < 9; ++k){
    size_t idx = base + (size_t)k*64;
    mp[idx] = msg[idx]*p;
  }
}

// ---------- energies & dipoles ----------
__global__ void k_edip(const float* __restrict__ nf, const float* __restrict__ we,
                       const float* __restrict__ wd, const int* __restrict__ batch,
                       float* __restrict__ Etg, float* __restrict__ adp, float* __restrict__ td){
  int n = blockIdx.x, c = threadIdx.x;
  int g = batch[n];
  float v = nf[(size_t)n*576 + c]*we[c];
  #pragma unroll
  for (int o = 32; o; o >>= 1) v += __shfl_xor(v, o, 64);
  if (c == 0) atomicAdd(&Etg[g], v);
  #pragma unroll
  for (int j = 0; j < 3; ++j){
    float dv = nf[(size_t)n*576 + (size_t)(j+1)*64 + c]*wd[c];
    #pragma unroll
    for (int o = 32; o; o >>= 1) dv += __shfl_xor(dv, o, 64);
    if (c == 0){ adp[n*3+j] += dv; atomicAdd(&td[g*3+j], dv); }
  }
}

// ---------- backward init / helpers ----------
__global__ void k_init_gnf(float* __restrict__ g, const float* __restrict__ we){
  int i = blockIdx.x*256 + threadIdx.x;
  if (i >= NN*576) return;
  int kd = i % 576;
  g[i] = (kd < 64) ? we[kd] : 0.f;
}

__global__ void k_add_we(float* __restrict__ g, const float* __restrict__ we){
  int i = blockIdx.x*256 + threadIdx.x;
  if (i >= NN*64) return;
  int n = i >> 6, d = i & 63;
  g[(size_t)n*576 + d] += we[d];
}

// gmp (in place) -> gmsg; adds poly-path grad to k=0
__global__ void k_poly_bwd(float* __restrict__ gmp, const float* __restrict__ msg,
                           const float* __restrict__ wp){
  int n = blockIdx.x, c = threadIdx.x;
  size_t base = (size_t)n*576 + c;
  float s0 = msg[base];
  float p1 = wp[c*3+1], p2 = wp[c*3+2];
  float poly = fmaf(fmaf(p2, s0, p1), s0, wp[c*3+0]);
  float gp = 0.f;
  #pragma unroll
  for (int k = 0; k < 9; ++k){
    size_t idx = base + (size_t)k*64;
    float g = gmp[idx];
    gp = fmaf(g, msg[idx], gp);
    gmp[idx] = g*poly;
  }
  gmp[base] += gp*fmaf(2.f*p2, s0, p1);
}

// ---------- backward edge kernel ----------
__global__ __launch_bounds__(256) void k_edge_bwd(
    const float* __restrict__ ef, const float* __restrict__ sh, const float* __restrict__ rl,
    const float* __restrict__ uv, const float* __restrict__ nfprev, const float* __restrict__ gagg,
    const int* __restrict__ ei, const float* __restrict__ R1, const float* __restrict__ R2,
    const float* __restrict__ R2T, float* __restrict__ gnfprev, float* __restrict__ gpos, int need_gh){
  __shared__ float R1s[512];
  __shared__ float R2s[4096];
  __shared__ float R2Ts[4096];
  __shared__ float xch[4][64];
  for (int i = threadIdx.x; i < 512;  i += 256) R1s[i] = R1[i];
  for (int i = threadIdx.x; i < 4096; i += 256){ R2s[i] = R2[i]; R2Ts[i] = R2T[i]; }
  __syncthreads();
  int lane = threadIdx.x & 63, wv = threadIdx.x >> 6;
  int ebase = blockIdx.x*32 + wv*8;
  for (int it = 0; it < 8; ++it){
    int e = ebase + it;
    const float* efp = ef + (size_t)e*8;
    float a = 0.f;
    #pragma unroll
    for (int b = 0; b < 8; ++b) a = fmaf(efp[b], R1s[b*64+lane], a);
    float sg = 1.f/(1.f + __expf(-a));
    float sl = a*sg;
    xch[wv][lane] = sl;
    __syncthreads();
    float w = 0.f;
    #pragma unroll
    for (int j = 0; j < 64; ++j) w = fmaf(xch[wv][j], R2s[j*64+lane], w);
    __syncthreads();
    int s = ei[e], r = ei[NE + e];
    float h = nfprev[(size_t)s*576 + lane];
    const float* gp_ = gagg + (size_t)r*576 + lane;
    const float* shp = sh + (size_t)e*9;
    float gm[9], shv[9];
    #pragma unroll
    for (int k = 0; k < 9; ++k){ shv[k] = shp[k]; gm[k] = gp_[(size_t)k*64]*(1.f/16.f); }
    float S = 0.f;
    #pragma unroll
    for (int k = 0; k < 9; ++k) S = fmaf(gm[k], shv[k], S);
    float gw = h*S, gh = w*S;
    if (need_gh) atomicAdd(&gnfprev[(size_t)s*576 + lane], gh);
    float wh = w*h;
    float gshv[9];
    #pragma unroll
    for (int k = 0; k < 9; ++k){
      float v = gm[k]*wh;
      #pragma unroll
      for (int o = 32; o; o >>= 1) v += __shfl_xor(v, o, 64);
      gshv[k] = v;
    }
    // MLP backward
    xch[wv][lane] = gw;
    __syncthreads();
    float gsl = 0.f;
    #pragma unroll
    for (int c2 = 0; c2 < 64; ++c2) gsl = fmaf(xch[wv][c2], R2Ts[c2*64+lane], gsl);
    __syncthreads();
    float ga = gsl * sg * fmaf(a, 1.f - sg, 1.f);
    xch[wv][lane] = ga;
    __syncthreads();
    float gefb = 0.f;
    if (lane < 8){
      #pragma unroll
      for (int j = 0; j < 64; ++j) gefb = fmaf(xch[wv][j], R1s[lane*64+j], gefb);
    }
    __syncthreads();
    if (lane < 8) xch[wv][lane] = gefb;
    __syncthreads();
    if (lane == 0){
      float L = rl[e];
      float ux = uv[(size_t)e*3], uy = uv[(size_t)e*3+1], uz = uv[(size_t)e*3+2];
      float gr = 0.f;
      float ur = L*0.2f;
      if (ur < 1.f){
        float u2 = ur*ur, u4 = u2*u2, u5 = u4*ur;
        float fc = 1.f - 21.f*u5 + 35.f*u5*ur - 15.f*u5*u2;
        float omu = 1.f - ur;
        float dfc = -105.f*u4*omu*omu;           // d fc / d u
        float invr = 1.f/(L + 1e-9f);
        #pragma unroll
        for (int b = 0; b < 8; ++b){
          float nb = (float)(b+1);
          float arg = nb*PI_F*ur;
          float sn = sinf(arg), cs = cosf(arg);
          float bes = KBES*sn*invr;
          float dbes = KBES*(nb*PI_F*0.2f)*cs*invr - bes*invr;
          float defdr = dbes*fc + bes*dfc*0.2f;
          gr = fmaf(xch[wv][b], defdr, gr);
        }
      }
      float gux = S3*gshv[1] + S15*(uy*gshv[4] + uz*gshv[7] + ux*gshv[8]);
      float guy = S3*gshv[2] + S15*(ux*gshv[4] + uz*gshv[5] - uy*gshv[8]);
      float guz = S3*gshv[3] + S15*(uy*gshv[5] + ux*gshv[7]) + 3.f*S5*uz*gshv[6];
      float dot = gux*ux + guy*uy + guz*uz;
      float invL = 1.f/L;
      float gvx = (gux - dot*ux)*invL + gr*ux;
      float gvy = (guy - dot*uy)*invL + gr*uy;
      float gvz = (guz - dot*uz)*invL + gr*uz;
      atomicAdd(&gpos[s*3+0],  gvx); atomicAdd(&gpos[s*3+1],  gvy); atomicAdd(&gpos[s*3+2],  gvz);
      atomicAdd(&gpos[r*3+0], -gvx); atomicAdd(&gpos[r*3+1], -gvy); atomicAdd(&gpos[r*3+2], -gvz);
    }
    __syncthreads();
  }
}

// ---------- charge dipole term ----------
__global__ void k_charge(const float* __restrict__ q, const float* __restrict__ pos,
                         const int* __restrict__ batch, float* __restrict__ td){
  int n = blockIdx.x*256 + threadIdx.x;
  if (n >= NN) return;
  int g = batch[n];
  float qq = q[n];
  #pragma unroll
  for (int j = 0; j < 3; ++j) atomicAdd(&td[g*3+j], qq*pos[n*3+j]);
}

// ---------- final write-out (bf16 or f32 per flag) ----------
__global__ void k_writeout(const float* __restrict__ e0g, const float* __restrict__ Etg,
                           const float* __restrict__ td, const float* __restrict__ adp,
                           const float* __restrict__ gpos, void* __restrict__ outv,
                           const int* __restrict__ flag){
  int i = blockIdx.x*256 + threadIdx.x;
  const int total = NG + NG*3 + NN*3 + NG*3 + NN*3; // 60112
  if (i >= total) return;
  float v;
  if (i < 16){
    v = e0g[i] + Etg[i] + Etg[16+i];
  } else if (i < 64){
    int j = i - 16; int g = j/3, t = j - g*3;
    v = (t == 0) ? e0g[g] : Etg[(t-1)*16 + g];
  } else if (i < 64 + NN*3){
    v = -gpos[i-64];
  } else if (i < 64 + NN*3 + 48){
    v = td[i - (64 + NN*3)];
  } else {
    v = adp[i - (64 + NN*3 + 48)];
  }
  if (flag[0]) ((__hip_bfloat16*)outv)[i] = __float2bfloat16(v);
  else         ((float*)outv)[i] = v;
}

extern "C" void kernel_launch(void* const* d_in, const int* in_sizes, int n_in,
                              void* d_out, int out_size, void* d_ws, size_t ws_size,
                              hipStream_t stream) {
  if (ws_size < WS_FLOATS*sizeof(float)) return; // need ~155 MB
  const int* ei    = (const int*)d_in[14];
  const int* batch = (const int*)d_in[15];
  float* ws = (float*)d_ws;
  int* flag = (int*)(ws + O_FLAG);

  // zero accumulators (includes flag slot; k_detect overwrites before use)
  hipMemsetAsync(ws + OFF_ACC, 0, ACC_FLOATS*sizeof(float), stream);
  k_detect<<<1, 256, 0, stream>>>((const unsigned*)d_in[1], flag);

  auto load = [&](int idx, size_t off, int n){
    k_load<<<(n+255)/256, 256, 0, stream>>>(d_in[idx], ws+off, n, flag);
  };
  load(0,  OFF_PIN, NN*3);
  load(1,  OFF_ATT, NN*NZ);
  load(2,  OFF_CHG, NN);
  load(3,  OFF_SHF, NE*3);
  load(4,  O_WEMB,  NZ*64);
  load(5,  O_AE,    NZ);
  load(6,  O_R1,    NT*NBES*64);
  load(7,  O_R2,    NT*64*64);
  load(8,  O_WMIX,  NT*3*64*64);
  load(9,  O_WSC,   NT*3*64*64);
  load(10, O_WPOLY, NT*64*3);
  load(11, O_WPROD, NT*3*64*64);
  load(12, O_WE,    NT*64);
  load(13, O_WD,    NT*64);
  k_transpose64<<<(2*4096+255)/256, 256, 0, stream>>>(ws+O_R2,   ws+O_R2T,   2);
  k_transpose64<<<(6*4096+255)/256, 256, 0, stream>>>(ws+O_WMIX, ws+O_WMIXT, 6);
  k_transpose64<<<(6*4096+255)/256, 256, 0, stream>>>(ws+O_WSC,  ws+O_WSCT,  6);
  k_transpose64<<<(6*4096+255)/256, 256, 0, stream>>>(ws+O_WPROD,ws+O_WPRODT,6);

  k_geom<<<(NE+255)/256, 256, 0, stream>>>(ws+OFF_PIN, ws+OFF_SHF, ei, ws+OFF_SH, ws+OFF_EF, ws+OFF_RL, ws+OFF_UV);
  k_init_nodes<<<NN, 64, 0, stream>>>(ws+OFF_ATT, ws+O_WEMB, ws+O_AE, batch, ws+OFF_NF0, ws+O_E0G);

  const size_t NF[3]  = {OFF_NF0, OFF_NF1, OFF_NF2};
  const size_t MSG[2] = {OFF_MSG0, OFF_MSG1};
  dim3 ling(NN/16, 9);

  // ---------- forward layers ----------
  for (int t = 0; t < NT; ++t){
    hipMemsetAsync(ws + OFF_AGG, 0, NFSZ*sizeof(float), stream);
    k_edge_fwd<<<NE/32, 256, 0, stream>>>(ws+OFF_EF, ws+OFF_SH, ws+NF[t], ei,
                                          ws+O_R1 + (size_t)t*512, ws+O_R2 + (size_t)t*4096, ws+OFF_AGG);
    k_lin<<<ling, 256, 0, stream>>>(ws+OFF_AGG, ws+O_WMIX + (size_t)t*12288, ws+MSG[t], 0);
    k_lin<<<ling, 256, 0, stream>>>(ws+NF[t],   ws+O_WSC  + (size_t)t*12288, ws+NF[t+1], 0);
    k_poly<<<NN, 64, 0, stream>>>(ws+MSG[t], ws+O_WPOLY + (size_t)t*192, ws+OFF_AGG);
    k_lin<<<ling, 256, 0, stream>>>(ws+OFF_AGG, ws+O_WPROD + (size_t)t*12288, ws+NF[t+1], 1);
    k_edip<<<NN, 64, 0, stream>>>(ws+NF[t+1], ws+O_WE + (size_t)t*64, ws+O_WD + (size_t)t*64,
                                  batch, ws+O_ETG + (size_t)t*16, ws+O_ADP, ws+O_TD);
  }

  // ---------- backward ----------
  float* GA = ws + OFF_NF2;
  float* GB = ws + OFF_MSG1;
  k_init_gnf<<<(NN*576+255)/256, 256, 0, stream>>>(GA, ws+O_WE + (size_t)(NT-1)*64);

  // t = 1
  {
    int t = 1;
    k_lin<<<ling, 256, 0, stream>>>(GA, ws+O_WPRODT + (size_t)t*12288, ws+OFF_AGG, 0);
    k_poly_bwd<<<NN, 64, 0, stream>>>(ws+OFF_AGG, ws+MSG[t], ws+O_WPOLY + (size_t)t*192);
    k_lin<<<ling, 256, 0, stream>>>(GA, ws+O_WSCT + (size_t)t*12288, GB, 0);          // gnfprev (sc path)
    k_lin<<<ling, 256, 0, stream>>>(ws+OFF_AGG, ws+O_WMIXT + (size_t)t*12288, GA, 0); // gagg into GA
    k_edge_bwd<<<NE/32, 256, 0, stream>>>(ws+OFF_EF, ws+OFF_SH, ws+OFF_RL, ws+OFF_UV,
                                          ws+NF[t], GA, ei,
                                          ws+O_R1 + (size_t)t*512, ws+O_R2 + (size_t)t*4096,
                                          ws+O_R2T + (size_t)t*4096, GB, ws+O_GPOS, 1);
    k_add_we<<<(NN*64+255)/256, 256, 0, stream>>>(GB, ws+O_WE + (size_t)(t-1)*64);
  }
  // t = 0
  {
    int t = 0;
    k_lin<<<ling, 256, 0, stream>>>(GB, ws+O_WPRODT + (size_t)t*12288, ws+OFF_AGG, 0);
    k_poly_bwd<<<NN, 64, 0, stream>>>(ws+OFF_AGG, ws+MSG[t], ws+O_WPOLY + (size_t)t*192);
    k_lin<<<ling, 256, 0, stream>>>(ws+OFF_AGG, ws+O_WMIXT + (size_t)t*12288, GA, 0); // gagg
    k_edge_bwd<<<NE/32, 256, 0, stream>>>(ws+OFF_EF, ws+OFF_SH, ws+OFF_RL, ws+OFF_UV,
                                          ws+NF[t], GA, ei,
                                          ws+O_R1 + (size_t)t*512, ws+O_R2 + (size_t)t*4096,
                                          ws+O_R2T + (size_t)t*4096, GB /*unused*/, ws+O_GPOS, 0);
  }

  k_charge<<<(NN+255)/256, 256, 0, stream>>>(ws+OFF_CHG, ws+OFF_PIN, batch, ws+O_TD);
  k_writeout<<<(60112+255)/256, 256, 0, stream>>>(ws+O_E0G, ws+O_ETG, ws+O_TD, ws+O_ADP, ws+O_GPOS, d_out, flag);
}

// Round 3
// 3040.112 us; speedup vs baseline: 1.0808x; 1.0808x over previous
//
#include <hip/hip_runtime.h>
#include <hip/hip_bf16.h>

#define NN 10000
#define NE 160000
#define NZ 10
#define NC 64
#define NBES 8
#define NG 16
#define NT 2

static constexpr float PI_F  = 3.14159265358979323846f;
static constexpr float KBES  = 0.63245553203367587f;  // sqrt(2/5)
static constexpr float S3    = 1.73205080756887729f;
static constexpr float S5    = 2.23606797749978969f;
static constexpr float S15   = 3.87298334620741688f;

// ---- workspace layout (float offsets) ----
static constexpr size_t OFF_SH   = 0;
static constexpr size_t OFF_EF   = OFF_SH  + (size_t)NE*9;
static constexpr size_t OFF_RL   = OFF_EF  + (size_t)NE*8;
static constexpr size_t OFF_UV   = OFF_RL  + (size_t)NE;
static constexpr size_t OFF_PIN  = OFF_UV  + (size_t)NE*3;   // positions f32
static constexpr size_t OFF_ATT  = OFF_PIN + (size_t)NN*3;   // node_attrs f32
static constexpr size_t OFF_CHG  = OFF_ATT + (size_t)NN*NZ;  // charges f32
static constexpr size_t OFF_SHF  = OFF_CHG + (size_t)NN;     // shifts f32
static constexpr size_t NFSZ     = (size_t)NN*576;
static constexpr size_t OFF_NF0  = OFF_SHF + (size_t)NE*3;
static constexpr size_t OFF_NF1  = OFF_NF0 + NFSZ;
static constexpr size_t OFF_NF2  = OFF_NF1 + NFSZ;   // aliased as gnf "A" in bwd
static constexpr size_t OFF_MSG0 = OFF_NF2 + NFSZ;
static constexpr size_t OFF_MSG1 = OFF_MSG0+ NFSZ;   // aliased as gnf "B" in bwd
static constexpr size_t OFF_AGG  = OFF_MSG1+ NFSZ;   // agg / mp / gmp / gmsg scratch
static constexpr size_t OFF_W    = OFF_AGG + NFSZ;
static constexpr size_t O_WEMB   = OFF_W;
static constexpr size_t O_AE     = O_WEMB + 640;
static constexpr size_t O_R1     = O_AE   + 16;
static constexpr size_t O_R2     = O_R1   + 1024;
static constexpr size_t O_R2T    = O_R2   + 8192;
static constexpr size_t O_WMIX   = O_R2T  + 8192;
static constexpr size_t O_WMIXT  = O_WMIX + 24576;
static constexpr size_t O_WSC    = O_WMIXT+ 24576;
static constexpr size_t O_WSCT   = O_WSC  + 24576;
static constexpr size_t O_WPROD  = O_WSCT + 24576;
static constexpr size_t O_WPRODT = O_WPROD+ 24576;
static constexpr size_t O_WPOLY  = O_WPRODT+24576;
static constexpr size_t O_WE     = O_WPOLY+ 384;
static constexpr size_t O_WD     = O_WE   + 128;
static constexpr size_t OFF_ACC  = O_WD   + 128;
static constexpr size_t O_E0G    = OFF_ACC;          // 16
static constexpr size_t O_ETG    = O_E0G + 16;       // 32 ([t][g])
static constexpr size_t O_TD     = O_ETG + 32;       // 48
static constexpr size_t O_ADP    = O_TD  + 48;       // N*3
static constexpr size_t O_GPOS   = O_ADP + (size_t)NN*3;
static constexpr size_t O_GVEC   = O_GPOS+ (size_t)NN*3;     // per-edge dE/dvec (NOT zeroed)
static constexpr size_t ACC_FLOATS = O_GVEC - OFF_ACC;       // zeroed region
static constexpr size_t O_FLAG   = O_GVEC + (size_t)NE*3;    // dtype flag (int)
static constexpr size_t WS_FLOATS= O_FLAG + 4;

// ---------- dtype detection: node_attrs is one-hot {0,1} ----------
__global__ void k_detect(const unsigned* __restrict__ raw, int* __restrict__ flag){
  __shared__ int found;
  if (threadIdx.x == 0) found = 0;
  __syncthreads();
  for (int i = threadIdx.x; i < 4096; i += 256){
    unsigned w = raw[i];
    if (w == 0x00003F80u || w == 0x3F803F80u) found = 1;
  }
  __syncthreads();
  if (threadIdx.x == 0) flag[0] = found;
}

// ---------- generic loader: src (bf16 or f32 per flag) -> f32 ----------
__global__ void k_load(const void* __restrict__ src, float* __restrict__ dst, int n,
                       const int* __restrict__ flag){
  int i = blockIdx.x*256 + threadIdx.x;
  if (i >= n) return;
  if (flag[0]) dst[i] = __bfloat162float(((const __hip_bfloat16*)src)[i]);
  else         dst[i] = ((const float*)src)[i];
}

// transpose m 64x64 matrices
__global__ void k_transpose64(const float* __restrict__ s, float* __restrict__ d, int m){
  int i = blockIdx.x*256 + threadIdx.x;
  if (i >= m*4096) return;
  int mm = i >> 12, r = (i >> 6) & 63, c = i & 63;
  d[(size_t)mm*4096 + (size_t)c*64 + r] = s[(size_t)mm*4096 + (size_t)r*64 + c];
}

// ---------- edge geometry ----------
__global__ void k_geom(const float* __restrict__ pos, const float* __restrict__ shifts,
                       const int* __restrict__ ei, float* __restrict__ sh, float* __restrict__ ef,
                       float* __restrict__ rl, float* __restrict__ uv){
  int e = blockIdx.x*256 + threadIdx.x;
  if (e >= NE) return;
  int s = ei[e], r = ei[NE + e];
  float vx = pos[s*3+0] - pos[r*3+0] + shifts[(size_t)e*3+0];
  float vy = pos[s*3+1] - pos[r*3+1] + shifts[(size_t)e*3+1];
  float vz = pos[s*3+2] - pos[r*3+2] + shifts[(size_t)e*3+2];
  float L = sqrtf(vx*vx + vy*vy + vz*vz + 1e-12f);
  float inv = 1.f / L;
  float x = vx*inv, y = vy*inv, z = vz*inv;
  float* shp = sh + (size_t)e*9;
  shp[0] = 1.f;     shp[1] = S3*x;    shp[2] = S3*y;   shp[3] = S3*z;
  shp[4] = S15*x*y; shp[5] = S15*y*z; shp[6] = 0.5f*S5*(3.f*z*z - 1.f);
  shp[7] = S15*x*z; shp[8] = 0.5f*S15*(x*x - y*y);
  rl[e] = L;
  uv[(size_t)e*3+0] = x; uv[(size_t)e*3+1] = y; uv[(size_t)e*3+2] = z;
  float ur = L * 0.2f;
  float fc = 0.f;
  if (ur < 1.f){
    float u2 = ur*ur, u4 = u2*u2, u5 = u4*ur;
    fc = 1.f - 21.f*u5 + 35.f*u5*ur - 15.f*u5*u2;
  }
  float invr = 1.f / (L + 1e-9f);
  float* efp = ef + (size_t)e*8;
  #pragma unroll
  for (int b = 0; b < 8; ++b){
    float arg = (float)(b+1) * PI_F * ur;
    efp[b] = KBES * sinf(arg) * invr * fc;
  }
}

// ---------- node init ----------
__global__ void k_init_nodes(const float* __restrict__ attrs, const float* __restrict__ Wemb,
                             const float* __restrict__ ae, const int* __restrict__ batch,
                             float* __restrict__ nf0, float* __restrict__ e0g){
  int n = blockIdx.x, c = threadIdx.x;
  float acc = 0.f;
  #pragma unroll
  for (int z = 0; z < NZ; ++z) acc = fmaf(attrs[(size_t)n*NZ+z], Wemb[z*64+c], acc);
  size_t base = (size_t)n*576;
  nf0[base + c] = acc;
  #pragma unroll
  for (int k = 1; k < 9; ++k) nf0[base + (size_t)k*64 + c] = 0.f;
  if (c == 0){
    float e = 0.f;
    #pragma unroll
    for (int z = 0; z < NZ; ++z) e = fmaf(attrs[(size_t)n*NZ+z], ae[z], e);
    atomicAdd(&e0g[batch[n]], e);
  }
}

// ---------- forward edge kernel (wave-synchronous, no block barriers) ----------
__global__ __launch_bounds__(256) void k_edge_fwd(
    const float* __restrict__ ef, const float* __restrict__ sh, const float* __restrict__ nfprev,
    const int* __restrict__ ei, const float* __restrict__ R1, const float* __restrict__ R2,
    float* __restrict__ agg){
  __shared__ float R1s[512];
  __shared__ float R2s[4096];
  __shared__ float sa[4][64];
  for (int i = threadIdx.x; i < 512;  i += 256) R1s[i] = R1[i];
  for (int i = threadIdx.x; i < 4096; i += 256) R2s[i] = R2[i];
  __syncthreads();
  int lane = threadIdx.x & 63, wv = threadIdx.x >> 6;
  int ebase = blockIdx.x*32 + wv*8;
  for (int it = 0; it < 8; ++it){
    int e = ebase + it;
    const float* efp = ef + (size_t)e*8;
    float a = 0.f;
    #pragma unroll
    for (int b = 0; b < 8; ++b) a = fmaf(efp[b], R1s[b*64+lane], a);
    float sg = 1.f/(1.f + __expf(-a));
    sa[wv][lane] = a*sg;               // wave-private slice; wave64 lockstep
    __builtin_amdgcn_wave_barrier();
    float w = 0.f;
    #pragma unroll
    for (int j = 0; j < 64; ++j) w = fmaf(sa[wv][j], R2s[j*64+lane], w);
    __builtin_amdgcn_wave_barrier();
    int s = ei[e], r = ei[NE + e];
    float h = nfprev[(size_t)s*576 + lane];
    float base = w*h*(1.f/16.f);
    const float* shp = sh + (size_t)e*9;
    float* ap = agg + (size_t)r*576 + lane;
    #pragma unroll
    for (int k = 0; k < 9; ++k) atomicAdd(ap + (size_t)k*64, base*shp[k]);
  }
}

// ---------- per-l linear ----------
__global__ __launch_bounds__(256) void k_lin(const float* __restrict__ in, const float* __restrict__ W3,
                                             float* __restrict__ out, int accum){
  __shared__ float Wl[4096];
  int k = blockIdx.y;
  int l = (k==0) ? 0 : ((k<4) ? 1 : 2);
  const float* W = W3 + (size_t)l*4096;
  for (int i = threadIdx.x; i < 4096; i += 256) Wl[i] = W[i];
  __syncthreads();
  int d = threadIdx.x & 63, sub = threadIdx.x >> 6;
  int nbase = blockIdx.x*16;
  for (int i = 0; i < 4; ++i){
    int n = nbase + sub*4 + i;
    const float* inr = in + (size_t)n*576 + (size_t)k*64;
    float acc = 0.f;
    #pragma unroll
    for (int c = 0; c < 64; ++c) acc = fmaf(inr[c], Wl[c*64+d], acc);
    float* o = out + (size_t)n*576 + (size_t)k*64 + d;
    if (accum) *o += acc; else *o = acc;
  }
}

// ---------- poly gate forward ----------
__global__ void k_poly(const float* __restrict__ msg, const float* __restrict__ wp, float* __restrict__ mp){
  int n = blockIdx.x, c = threadIdx.x;
  size_t base = (size_t)n*576 + c;
  float s0 = msg[base];
  float p = fmaf(fmaf(wp[c*3+2], s0, wp[c*3+1]), s0, wp[c*3+0]);
  #pragma unroll
  for (int k = 0; k < 9; ++k){
    size_t idx = base + (size_t)k*64;
    mp[idx] = msg[idx]*p;
  }
}

// ---------- energies & dipoles ----------
__global__ void k_edip(const float* __restrict__ nf, const float* __restrict__ we,
                       const float* __restrict__ wd, const int* __restrict__ batch,
                       float* __restrict__ Etg, float* __restrict__ adp, float* __restrict__ td){
  int n = blockIdx.x, c = threadIdx.x;
  int g = batch[n];
  float v = nf[(size_t)n*576 + c]*we[c];
  #pragma unroll
  for (int o = 32; o; o >>= 1) v += __shfl_xor(v, o, 64);
  if (c == 0) atomicAdd(&Etg[g], v);
  #pragma unroll
  for (int j = 0; j < 3; ++j){
    float dv = nf[(size_t)n*576 + (size_t)(j+1)*64 + c]*wd[c];
    #pragma unroll
    for (int o = 32; o; o >>= 1) dv += __shfl_xor(dv, o, 64);
    if (c == 0){ adp[n*3+j] += dv; atomicAdd(&td[g*3+j], dv); }
  }
}

// ---------- backward init / helpers ----------
__global__ void k_init_gnf(float* __restrict__ g, const float* __restrict__ we){
  int i = blockIdx.x*256 + threadIdx.x;
  if (i >= NN*576) return;
  int kd = i % 576;
  g[i] = (kd < 64) ? we[kd] : 0.f;
}

__global__ void k_add_we(float* __restrict__ g, const float* __restrict__ we){
  int i = blockIdx.x*256 + threadIdx.x;
  if (i >= NN*64) return;
  int n = i >> 6, d = i & 63;
  g[(size_t)n*576 + d] += we[d];
}

// gmp (in place) -> gmsg; adds poly-path grad to k=0
__global__ void k_poly_bwd(float* __restrict__ gmp, const float* __restrict__ msg,
                           const float* __restrict__ wp){
  int n = blockIdx.x, c = threadIdx.x;
  size_t base = (size_t)n*576 + c;
  float s0 = msg[base];
  float p1 = wp[c*3+1], p2 = wp[c*3+2];
  float poly = fmaf(fmaf(p2, s0, p1), s0, wp[c*3+0]);
  float gp = 0.f;
  #pragma unroll
  for (int k = 0; k < 9; ++k){
    size_t idx = base + (size_t)k*64;
    float g = gmp[idx];
    gp = fmaf(g, msg[idx], gp);
    gmp[idx] = g*poly;
  }
  gmp[base] += gp*fmaf(2.f*p2, s0, p1);
}

// ---------- backward edge kernel (wave-synchronous) ----------
__global__ __launch_bounds__(256) void k_edge_bwd(
    const float* __restrict__ ef, const float* __restrict__ sh, const float* __restrict__ rl,
    const float* __restrict__ uv, const float* __restrict__ nfprev, const float* __restrict__ gagg,
    const int* __restrict__ ei, const float* __restrict__ R1, const float* __restrict__ R2,
    const float* __restrict__ R2T, float* __restrict__ gnfprev, float* __restrict__ gvec,
    int need_gh, int accum){
  __shared__ float R1s[512];
  __shared__ float R2s[4096];
  __shared__ float R2Ts[4096];
  __shared__ float xch[4][64];
  for (int i = threadIdx.x; i < 512;  i += 256) R1s[i] = R1[i];
  for (int i = threadIdx.x; i < 4096; i += 256){ R2s[i] = R2[i]; R2Ts[i] = R2T[i]; }
  __syncthreads();
  int lane = threadIdx.x & 63, wv = threadIdx.x >> 6;
  int ebase = blockIdx.x*32 + wv*8;
  for (int it = 0; it < 8; ++it){
    int e = ebase + it;
    const float* efp = ef + (size_t)e*8;
    float a = 0.f;
    #pragma unroll
    for (int b = 0; b < 8; ++b) a = fmaf(efp[b], R1s[b*64+lane], a);
    float sg = 1.f/(1.f + __expf(-a));
    float sl = a*sg;
    xch[wv][lane] = sl;
    __builtin_amdgcn_wave_barrier();
    float w = 0.f;
    #pragma unroll
    for (int j = 0; j < 64; ++j) w = fmaf(xch[wv][j], R2s[j*64+lane], w);
    __builtin_amdgcn_wave_barrier();
    int s = ei[e], r = ei[NE + e];
    float h = nfprev[(size_t)s*576 + lane];
    const float* gp_ = gagg + (size_t)r*576 + lane;
    const float* shp = sh + (size_t)e*9;
    float gm[9], shv[9];
    #pragma unroll
    for (int k = 0; k < 9; ++k){ shv[k] = shp[k]; gm[k] = gp_[(size_t)k*64]*(1.f/16.f); }
    float S = 0.f;
    #pragma unroll
    for (int k = 0; k < 9; ++k) S = fmaf(gm[k], shv[k], S);
    float gw = h*S, gh = w*S;
    if (need_gh) atomicAdd(&gnfprev[(size_t)s*576 + lane], gh);
    float wh = w*h;
    float gshv[9];
    #pragma unroll
    for (int k = 0; k < 9; ++k){
      float v = gm[k]*wh;
      #pragma unroll
      for (int o = 32; o; o >>= 1) v += __shfl_xor(v, o, 64);
      gshv[k] = v;
    }
    // MLP backward
    xch[wv][lane] = gw;
    __builtin_amdgcn_wave_barrier();
    float gsl = 0.f;
    #pragma unroll
    for (int c2 = 0; c2 < 64; ++c2) gsl = fmaf(xch[wv][c2], R2Ts[c2*64+lane], gsl);
    __builtin_amdgcn_wave_barrier();
    float ga = gsl * sg * fmaf(a, 1.f - sg, 1.f);
    xch[wv][lane] = ga;
    __builtin_amdgcn_wave_barrier();
    float gefb = 0.f;
    if (lane < 8){
      #pragma unroll
      for (int j = 0; j < 64; ++j) gefb = fmaf(xch[wv][j], R1s[lane*64+j], gefb);
    }
    __builtin_amdgcn_wave_barrier();
    if (lane < 8) xch[wv][lane] = gefb;
    __builtin_amdgcn_wave_barrier();
    // geometry gradient — all lanes compute redundantly (uniform values)
    {
      float L = rl[e];
      float ux = uv[(size_t)e*3], uy = uv[(size_t)e*3+1], uz = uv[(size_t)e*3+2];
      float gr = 0.f;
      float ur = L*0.2f;
      if (ur < 1.f){
        float u2 = ur*ur, u4 = u2*u2, u5 = u4*ur;
        float fc = 1.f - 21.f*u5 + 35.f*u5*ur - 15.f*u5*u2;
        float omu = 1.f - ur;
        float dfc = -105.f*u4*omu*omu;
        float invr = 1.f/(L + 1e-9f);
        #pragma unroll
        for (int b = 0; b < 8; ++b){
          float nb = (float)(b+1);
          float arg = nb*PI_F*ur;
          float sn = sinf(arg), cs = cosf(arg);
          float bes = KBES*sn*invr;
          float dbes = KBES*(nb*PI_F*0.2f)*cs*invr - bes*invr;
          float defdr = dbes*fc + bes*dfc*0.2f;
          gr = fmaf(xch[wv][b], defdr, gr);
        }
      }
      float gux = S3*gshv[1] + S15*(uy*gshv[4] + uz*gshv[7] + ux*gshv[8]);
      float guy = S3*gshv[2] + S15*(ux*gshv[4] + uz*gshv[5] - uy*gshv[8]);
      float guz = S3*gshv[3] + S15*(uy*gshv[5] + ux*gshv[7]) + 3.f*S5*uz*gshv[6];
      float dot = gux*ux + guy*uy + guz*uz;
      float invL = 1.f/L;
      float gvx = (gux - dot*ux)*invL + gr*ux;
      float gvy = (guy - dot*uy)*invL + gr*uy;
      float gvz = (guz - dot*uz)*invL + gr*uz;
      if (lane < 3){
        float comp = (lane==0) ? gvx : ((lane==1) ? gvy : gvz);
        size_t gi = (size_t)e*3 + lane;
        if (accum) gvec[gi] += comp; else gvec[gi] = comp;
      }
    }
    __builtin_amdgcn_wave_barrier();
  }
}

// ---------- deferred gpos scatter: one thread per edge, full-wave atomics ----------
__global__ void k_gscatter(const float* __restrict__ gvec, const int* __restrict__ ei,
                           float* __restrict__ gpos){
  int e = blockIdx.x*256 + threadIdx.x;
  if (e >= NE) return;
  int s = ei[e], r = ei[NE + e];
  float gx = gvec[(size_t)e*3], gy = gvec[(size_t)e*3+1], gz = gvec[(size_t)e*3+2];
  atomicAdd(&gpos[s*3+0],  gx); atomicAdd(&gpos[s*3+1],  gy); atomicAdd(&gpos[s*3+2],  gz);
  atomicAdd(&gpos[r*3+0], -gx); atomicAdd(&gpos[r*3+1], -gy); atomicAdd(&gpos[r*3+2], -gz);
}

// ---------- charge dipole term: wave-level segmented reduction (batch sorted) ----------
__global__ void k_charge(const float* __restrict__ q, const float* __restrict__ pos,
                         const int* __restrict__ batch, float* __restrict__ td){
  int n = blockIdx.x*256 + threadIdx.x;
  int lane = threadIdx.x & 63;
  bool valid = (n < NN);
  int g = valid ? batch[n] : -1;
  float px = 0.f, py = 0.f, pz = 0.f;
  if (valid){
    float qq = q[n];
    px = qq*pos[n*3+0]; py = qq*pos[n*3+1]; pz = qq*pos[n*3+2];
  }
  int g0 = __shfl(g, 0, 64), g63 = __shfl(g, 63, 64);
  if (g0 == g63 && g0 >= 0){
    #pragma unroll
    for (int o = 32; o; o >>= 1){
      px += __shfl_xor(px, o, 64); py += __shfl_xor(py, o, 64); pz += __shfl_xor(pz, o, 64);
    }
    if (lane == 0){
      atomicAdd(&td[g0*3+0], px); atomicAdd(&td[g0*3+1], py); atomicAdd(&td[g0*3+2], pz);
    }
  } else if (valid){
    atomicAdd(&td[g*3+0], px); atomicAdd(&td[g*3+1], py); atomicAdd(&td[g*3+2], pz);
  }
}

// ---------- final write-out ----------
__global__ void k_writeout(const float* __restrict__ e0g, const float* __restrict__ Etg,
                           const float* __restrict__ td, const float* __restrict__ adp,
                           const float* __restrict__ gpos, void* __restrict__ outv,
                           const int* __restrict__ flag){
  int i = blockIdx.x*256 + threadIdx.x;
  const int total = NG + NG*3 + NN*3 + NG*3 + NN*3; // 60112
  if (i >= total) return;
  float v;
  if (i < 16){
    v = e0g[i] + Etg[i] + Etg[16+i];
  } else if (i < 64){
    int j = i - 16; int g = j/3, t = j - g*3;
    v = (t == 0) ? e0g[g] : Etg[(t-1)*16 + g];
  } else if (i < 64 + NN*3){
    v = -gpos[i-64];
  } else if (i < 64 + NN*3 + 48){
    v = td[i - (64 + NN*3)];
  } else {
    v = adp[i - (64 + NN*3 + 48)];
  }
  if (flag[0]) ((__hip_bfloat16*)outv)[i] = __float2bfloat16(v);
  else         ((float*)outv)[i] = v;
}

extern "C" void kernel_launch(void* const* d_in, const int* in_sizes, int n_in,
                              void* d_out, int out_size, void* d_ws, size_t ws_size,
                              hipStream_t stream) {
  if (ws_size < WS_FLOATS*sizeof(float)) return; // need ~157 MB
  const int* ei    = (const int*)d_in[14];
  const int* batch = (const int*)d_in[15];
  float* ws = (float*)d_ws;
  int* flag = (int*)(ws + O_FLAG);

  hipMemsetAsync(ws + OFF_ACC, 0, ACC_FLOATS*sizeof(float), stream);
  k_detect<<<1, 256, 0, stream>>>((const unsigned*)d_in[1], flag);

  auto load = [&](int idx, size_t off, int n){
    k_load<<<(n+255)/256, 256, 0, stream>>>(d_in[idx], ws+off, n, flag);
  };
  load(0,  OFF_PIN, NN*3);
  load(1,  OFF_ATT, NN*NZ);
  load(2,  OFF_CHG, NN);
  load(3,  OFF_SHF, NE*3);
  load(4,  O_WEMB,  NZ*64);
  load(5,  O_AE,    NZ);
  load(6,  O_R1,    NT*NBES*64);
  load(7,  O_R2,    NT*64*64);
  load(8,  O_WMIX,  NT*3*64*64);
  load(9,  O_WSC,   NT*3*64*64);
  load(10, O_WPOLY, NT*64*3);
  load(11, O_WPROD, NT*3*64*64);
  load(12, O_WE,    NT*64);
  load(13, O_WD,    NT*64);
  k_transpose64<<<(2*4096+255)/256, 256, 0, stream>>>(ws+O_R2,   ws+O_R2T,   2);
  k_transpose64<<<(6*4096+255)/256, 256, 0, stream>>>(ws+O_WMIX, ws+O_WMIXT, 6);
  k_transpose64<<<(6*4096+255)/256, 256, 0, stream>>>(ws+O_WSC,  ws+O_WSCT,  6);
  k_transpose64<<<(6*4096+255)/256, 256, 0, stream>>>(ws+O_WPROD,ws+O_WPRODT,6);

  k_geom<<<(NE+255)/256, 256, 0, stream>>>(ws+OFF_PIN, ws+OFF_SHF, ei, ws+OFF_SH, ws+OFF_EF, ws+OFF_RL, ws+OFF_UV);
  k_init_nodes<<<NN, 64, 0, stream>>>(ws+OFF_ATT, ws+O_WEMB, ws+O_AE, batch, ws+OFF_NF0, ws+O_E0G);

  const size_t NF[3]  = {OFF_NF0, OFF_NF1, OFF_NF2};
  const size_t MSG[2] = {OFF_MSG0, OFF_MSG1};
  dim3 ling(NN/16, 9);

  // ---------- forward layers ----------
  for (int t = 0; t < NT; ++t){
    hipMemsetAsync(ws + OFF_AGG, 0, NFSZ*sizeof(float), stream);
    k_edge_fwd<<<NE/32, 256, 0, stream>>>(ws+OFF_EF, ws+OFF_SH, ws+NF[t], ei,
                                          ws+O_R1 + (size_t)t*512, ws+O_R2 + (size_t)t*4096, ws+OFF_AGG);
    k_lin<<<ling, 256, 0, stream>>>(ws+OFF_AGG, ws+O_WMIX + (size_t)t*12288, ws+MSG[t], 0);
    k_lin<<<ling, 256, 0, stream>>>(ws+NF[t],   ws+O_WSC  + (size_t)t*12288, ws+NF[t+1], 0);
    k_poly<<<NN, 64, 0, stream>>>(ws+MSG[t], ws+O_WPOLY + (size_t)t*192, ws+OFF_AGG);
    k_lin<<<ling, 256, 0, stream>>>(ws+OFF_AGG, ws+O_WPROD + (size_t)t*12288, ws+NF[t+1], 1);
    k_edip<<<NN, 64, 0, stream>>>(ws+NF[t+1], ws+O_WE + (size_t)t*64, ws+O_WD + (size_t)t*64,
                                  batch, ws+O_ETG + (size_t)t*16, ws+O_ADP, ws+O_TD);
  }

  // ---------- backward ----------
  float* GA = ws + OFF_NF2;
  float* GB = ws + OFF_MSG1;
  k_init_gnf<<<(NN*576+255)/256, 256, 0, stream>>>(GA, ws+O_WE + (size_t)(NT-1)*64);

  // t = 1
  {
    int t = 1;
    k_lin<<<ling, 256, 0, stream>>>(GA, ws+O_WPRODT + (size_t)t*12288, ws+OFF_AGG, 0);
    k_poly_bwd<<<NN, 64, 0, stream>>>(ws+OFF_AGG, ws+MSG[t], ws+O_WPOLY + (size_t)t*192);
    k_lin<<<ling, 256, 0, stream>>>(GA, ws+O_WSCT + (size_t)t*12288, GB, 0);          // gnfprev (sc path)
    k_lin<<<ling, 256, 0, stream>>>(ws+OFF_AGG, ws+O_WMIXT + (size_t)t*12288, GA, 0); // gagg into GA
    k_edge_bwd<<<NE/32, 256, 0, stream>>>(ws+OFF_EF, ws+OFF_SH, ws+OFF_RL, ws+OFF_UV,
                                          ws+NF[t], GA, ei,
                                          ws+O_R1 + (size_t)t*512, ws+O_R2 + (size_t)t*4096,
                                          ws+O_R2T + (size_t)t*4096, GB, ws+O_GVEC, 1, 0);
    k_add_we<<<(NN*64+255)/256, 256, 0, stream>>>(GB, ws+O_WE + (size_t)(t-1)*64);
  }
  // t = 0
  {
    int t = 0;
    k_lin<<<ling, 256, 0, stream>>>(GB, ws+O_WPRODT + (size_t)t*12288, ws+OFF_AGG, 0);
    k_poly_bwd<<<NN, 64, 0, stream>>>(ws+OFF_AGG, ws+MSG[t], ws+O_WPOLY + (size_t)t*192);
    k_lin<<<ling, 256, 0, stream>>>(ws+OFF_AGG, ws+O_WMIXT + (size_t)t*12288, GA, 0); // gagg
    k_edge_bwd<<<NE/32, 256, 0, stream>>>(ws+OFF_EF, ws+OFF_SH, ws+OFF_RL, ws+OFF_UV,
                                          ws+NF[t], GA, ei,
                                          ws+O_R1 + (size_t)t*512, ws+O_R2 + (size_t)t*4096,
                                          ws+O_R2T + (size_t)t*4096, GB /*unused*/, ws+O_GVEC, 0, 1);
  }
  k_gscatter<<<(NE+255)/256, 256, 0, stream>>>(ws+O_GVEC, ei, ws+O_GPOS);

  k_charge<<<(NN+255)/256, 256, 0, stream>>>(ws+OFF_CHG, ws+OFF_PIN, batch, ws+O_TD);
  k_writeout<<<(60112+255)/256, 256, 0, stream>>>(ws+O_E0G, ws+O_ETG, ws+O_TD, ws+O_ADP, ws+O_GPOS, d_out, flag);
}

// Round 4
// 2652.515 us; speedup vs baseline: 1.2387x; 1.1461x over previous
//
#include <hip/hip_runtime.h>
#include <hip/hip_bf16.h>

#define NN 10000
#define NE 160000
#define NZ 10
#define NC 64
#define NBES 8
#define NG 16
#define NT 2

static constexpr float PI_F  = 3.14159265358979323846f;
static constexpr float KBES  = 0.63245553203367587f;  // sqrt(2/5)
static constexpr float S3    = 1.73205080756887729f;
static constexpr float S5    = 2.23606797749978969f;
static constexpr float S15   = 3.87298334620741688f;

// ---- workspace layout (float offsets) ----
static constexpr size_t OFF_SH   = 0;
static constexpr size_t OFF_EF   = OFF_SH  + (size_t)NE*9;
static constexpr size_t OFF_RL   = OFF_EF  + (size_t)NE*8;
static constexpr size_t OFF_UV   = OFF_RL  + (size_t)NE;
static constexpr size_t OFF_PIN  = OFF_UV  + (size_t)NE*3;
static constexpr size_t OFF_ATT  = OFF_PIN + (size_t)NN*3;
static constexpr size_t OFF_CHG  = OFF_ATT + (size_t)NN*NZ;
static constexpr size_t OFF_SHF  = OFF_CHG + (size_t)NN;
static constexpr size_t NFSZ     = (size_t)NN*576;
static constexpr size_t OFF_NF0  = OFF_SHF + (size_t)NE*3;
static constexpr size_t OFF_NF1  = OFF_NF0 + NFSZ;
static constexpr size_t OFF_NF2  = OFF_NF1 + NFSZ;   // aliased as gnf "A" in bwd
static constexpr size_t OFF_MSG0 = OFF_NF2 + NFSZ;
static constexpr size_t OFF_MSG1 = OFF_MSG0+ NFSZ;   // aliased as gnf "B" in bwd
static constexpr size_t OFF_AGG  = OFF_MSG1+ NFSZ;
static constexpr size_t OFF_W    = OFF_AGG + NFSZ;
static constexpr size_t O_WEMB   = OFF_W;
static constexpr size_t O_AE     = O_WEMB + 640;
static constexpr size_t O_R1     = O_AE   + 16;
static constexpr size_t O_R2     = O_R1   + 1024;
static constexpr size_t O_R2T    = O_R2   + 8192;
static constexpr size_t O_WMIX   = O_R2T  + 8192;
static constexpr size_t O_WMIXT  = O_WMIX + 24576;
static constexpr size_t O_WSC    = O_WMIXT+ 24576;
static constexpr size_t O_WSCT   = O_WSC  + 24576;
static constexpr size_t O_WPROD  = O_WSCT + 24576;
static constexpr size_t O_WPRODT = O_WPROD+ 24576;
static constexpr size_t O_WPOLY  = O_WPRODT+24576;
static constexpr size_t O_WE     = O_WPOLY+ 384;
static constexpr size_t O_WD     = O_WE   + 128;
static constexpr size_t OFF_ACC  = O_WD   + 128;
static constexpr size_t O_E0G    = OFF_ACC;
static constexpr size_t O_ETG    = O_E0G + 16;
static constexpr size_t O_TD     = O_ETG + 32;
static constexpr size_t O_ADP    = O_TD  + 48;
static constexpr size_t O_GPOS   = O_ADP + (size_t)NN*3;
static constexpr size_t O_GVEC   = O_GPOS+ (size_t)NN*3;     // per-edge dE/dvec (NOT zeroed)
static constexpr size_t ACC_FLOATS = O_GVEC - OFF_ACC;
static constexpr size_t O_FLAG   = O_GVEC + (size_t)NE*3;
static constexpr size_t WS1_FLOATS = O_FLAG + 4;             // v1 requirement (~157 MB)
// ---- v2 additions ----
static constexpr size_t O_WBUF  = WS1_FLOATS;                // E*64 radial weights / gh staging
static constexpr size_t O_OFFR  = O_WBUF + (size_t)NE*64;    // ints from here
static constexpr size_t O_OFFS  = O_OFFR + (NN+1);
static constexpr size_t O_CURR  = O_OFFS + (NN+1);           // counts then cursors (zeroed)
static constexpr size_t O_CURS  = O_CURR + NN;
static constexpr size_t O_LISTR = O_CURS + NN;
static constexpr size_t O_LISTS = O_LISTR + (size_t)NE;
static constexpr size_t WS2_FLOATS = O_LISTS + (size_t)NE;   // ~200 MB

__device__ __forceinline__ float rlane(float v, int l){
  return __int_as_float(__builtin_amdgcn_readlane(__float_as_int(v), l));
}

// ---------- dtype detection ----------
__global__ void k_detect(const unsigned* __restrict__ raw, int* __restrict__ flag){
  __shared__ int found;
  if (threadIdx.x == 0) found = 0;
  __syncthreads();
  for (int i = threadIdx.x; i < 4096; i += 256){
    unsigned w = raw[i];
    if (w == 0x00003F80u || w == 0x3F803F80u) found = 1;
  }
  __syncthreads();
  if (threadIdx.x == 0) flag[0] = found;
}

__global__ void k_load(const void* __restrict__ src, float* __restrict__ dst, int n,
                       const int* __restrict__ flag){
  int i = blockIdx.x*256 + threadIdx.x;
  if (i >= n) return;
  if (flag[0]) dst[i] = __bfloat162float(((const __hip_bfloat16*)src)[i]);
  else         dst[i] = ((const float*)src)[i];
}

__global__ void k_transpose64(const float* __restrict__ s, float* __restrict__ d, int m){
  int i = blockIdx.x*256 + threadIdx.x;
  if (i >= m*4096) return;
  int mm = i >> 12, r = (i >> 6) & 63, c = i & 63;
  d[(size_t)mm*4096 + (size_t)c*64 + r] = s[(size_t)mm*4096 + (size_t)r*64 + c];
}

// ---------- edge geometry ----------
__global__ void k_geom(const float* __restrict__ pos, const float* __restrict__ shifts,
                       const int* __restrict__ ei, float* __restrict__ sh, float* __restrict__ ef,
                       float* __restrict__ rl, float* __restrict__ uv){
  int e = blockIdx.x*256 + threadIdx.x;
  if (e >= NE) return;
  int s = ei[e], r = ei[NE + e];
  float vx = pos[s*3+0] - pos[r*3+0] + shifts[(size_t)e*3+0];
  float vy = pos[s*3+1] - pos[r*3+1] + shifts[(size_t)e*3+1];
  float vz = pos[s*3+2] - pos[r*3+2] + shifts[(size_t)e*3+2];
  float L = sqrtf(vx*vx + vy*vy + vz*vz + 1e-12f);
  float inv = 1.f / L;
  float x = vx*inv, y = vy*inv, z = vz*inv;
  float* shp = sh + (size_t)e*9;
  shp[0] = 1.f;     shp[1] = S3*x;    shp[2] = S3*y;   shp[3] = S3*z;
  shp[4] = S15*x*y; shp[5] = S15*y*z; shp[6] = 0.5f*S5*(3.f*z*z - 1.f);
  shp[7] = S15*x*z; shp[8] = 0.5f*S15*(x*x - y*y);
  rl[e] = L;
  uv[(size_t)e*3+0] = x; uv[(size_t)e*3+1] = y; uv[(size_t)e*3+2] = z;
  float ur = L * 0.2f;
  float fc = 0.f;
  if (ur < 1.f){
    float u2 = ur*ur, u4 = u2*u2, u5 = u4*ur;
    fc = 1.f - 21.f*u5 + 35.f*u5*ur - 15.f*u5*u2;
  }
  float invr = 1.f / (L + 1e-9f);
  float* efp = ef + (size_t)e*8;
  #pragma unroll
  for (int b = 0; b < 8; ++b){
    float arg = (float)(b+1) * PI_F * ur;
    efp[b] = KBES * sinf(arg) * invr * fc;
  }
}

// ---------- node init ----------
__global__ void k_init_nodes(const float* __restrict__ attrs, const float* __restrict__ Wemb,
                             const float* __restrict__ ae, const int* __restrict__ batch,
                             float* __restrict__ nf0, float* __restrict__ e0g){
  int n = blockIdx.x, c = threadIdx.x;
  float acc = 0.f;
  #pragma unroll
  for (int z = 0; z < NZ; ++z) acc = fmaf(attrs[(size_t)n*NZ+z], Wemb[z*64+c], acc);
  size_t base = (size_t)n*576;
  nf0[base + c] = acc;
  #pragma unroll
  for (int k = 1; k < 9; ++k) nf0[base + (size_t)k*64 + c] = 0.f;
  if (c == 0){
    float e = 0.f;
    #pragma unroll
    for (int z = 0; z < NZ; ++z) e = fmaf(attrs[(size_t)n*NZ+z], ae[z], e);
    atomicAdd(&e0g[batch[n]], e);
  }
}

// ================= CSR construction =================
__global__ void k_csr_count(const int* __restrict__ ei, int* __restrict__ cntr, int* __restrict__ cnts){
  int e = blockIdx.x*256 + threadIdx.x;
  if (e >= NE) return;
  atomicAdd(&cntr[ei[NE+e]], 1);
  atomicAdd(&cnts[ei[e]], 1);
}

__global__ void k_csr_scan(int* __restrict__ cntr, int* __restrict__ cnts,
                           int* __restrict__ offr, int* __restrict__ offs_){
  __shared__ int part[256];
  for (int q = 0; q < 2; ++q){
    int* c   = q ? cnts  : cntr;   // counts in, cursor out (in place)
    int* off = q ? offs_ : offr;
    const int chunk = (NN + 255)/256;
    int lo = threadIdx.x*chunk, hi = lo+chunk; if (hi > NN) hi = NN; if (lo > NN) lo = NN;
    int s = 0;
    for (int i = lo; i < hi; ++i) s += c[i];
    part[threadIdx.x] = s;
    __syncthreads();
    for (int o = 1; o < 256; o <<= 1){
      int v = (threadIdx.x >= o) ? part[threadIdx.x-o] : 0;
      __syncthreads();
      part[threadIdx.x] += v;
      __syncthreads();
    }
    int run = (threadIdx.x == 0) ? 0 : part[threadIdx.x-1];
    for (int i = lo; i < hi; ++i){
      int ci = c[i];
      off[i] = run; c[i] = run;   // c becomes cursor
      run += ci;
    }
    if (threadIdx.x == 255) off[NN] = run;
    __syncthreads();
  }
}

__global__ void k_csr_fill(const int* __restrict__ ei, int* __restrict__ curr, int* __restrict__ curs,
                           int* __restrict__ listr, int* __restrict__ lists){
  int e = blockIdx.x*256 + threadIdx.x;
  if (e >= NE) return;
  int pr = atomicAdd(&curr[ei[NE+e]], 1); listr[pr] = e;
  int ps = atomicAdd(&curs[ei[e]], 1);    lists[ps] = e;
}

// ================= v2: radial MLP (VGPR-resident, readlane matvec) =================
__global__ __launch_bounds__(256) void k_radial(
    const float* __restrict__ ef, const float* __restrict__ R1, const float* __restrict__ R2,
    float* __restrict__ wbuf){
  int lane = threadIdx.x & 63;
  int wid = blockIdx.x*4 + (threadIdx.x >> 6);
  int nw  = gridDim.x*4;
  float r1c[8], r2c[64];
  #pragma unroll
  for (int j = 0; j < 8; ++j)  r1c[j] = R1[j*64 + lane];
  #pragma unroll
  for (int j = 0; j < 64; ++j) r2c[j] = R2[j*64 + lane];
  for (int e = wid; e < NE; e += nw){
    float efv = ef[(size_t)e*8 + (lane & 7)];
    float a = 0.f;
    #pragma unroll
    for (int b = 0; b < 8; ++b) a = fmaf(rlane(efv, b), r1c[b], a);
    float sg = 1.f/(1.f + __expf(-a));
    float sl = a*sg;
    float w0 = 0.f, w1 = 0.f, w2 = 0.f, w3 = 0.f;
    #pragma unroll
    for (int j = 0; j < 64; j += 4){
      w0 = fmaf(rlane(sl, j  ), r2c[j  ], w0);
      w1 = fmaf(rlane(sl, j+1), r2c[j+1], w1);
      w2 = fmaf(rlane(sl, j+2), r2c[j+2], w2);
      w3 = fmaf(rlane(sl, j+3), r2c[j+3], w3);
    }
    wbuf[(size_t)e*64 + lane] = (w0+w1) + (w2+w3);
  }
}

// ================= v2: atomic-free aggregation via receiver CSR =================
__global__ __launch_bounds__(256) void k_agg(
    const float* __restrict__ wbuf, const float* __restrict__ sh, const float* __restrict__ nf,
    const int* __restrict__ ei, const int* __restrict__ offr, const int* __restrict__ listr,
    float* __restrict__ agg){
  int lane = threadIdx.x & 63;
  int wid = blockIdx.x*4 + (threadIdx.x >> 6);
  int nw  = gridDim.x*4;
  for (int n = wid; n < NN; n += nw){
    int lo = offr[n], hi = offr[n+1];
    float acc[9];
    #pragma unroll
    for (int k = 0; k < 9; ++k) acc[k] = 0.f;
    for (int i = lo; i < hi; ++i){
      int e = __builtin_amdgcn_readfirstlane(listr[i]);
      int s = __builtin_amdgcn_readfirstlane(ei[e]);
      float wh = wbuf[(size_t)e*64 + lane] * nf[(size_t)s*576 + lane];
      const float* shp = sh + (size_t)e*9;
      #pragma unroll
      for (int k = 0; k < 9; ++k) acc[k] = fmaf(wh, shp[k], acc[k]);
    }
    size_t ob = (size_t)n*576 + lane;
    #pragma unroll
    for (int k = 0; k < 9; ++k) agg[ob + (size_t)k*64] = acc[k]*(1.f/16.f);
  }
}

// ================= v2: per-edge backward (VGPR matvecs, no LDS) =================
// Reads w from wbuf; overwrites wbuf[e][c] with w*S (gh staging for sender gather).
__global__ __launch_bounds__(256) void k_edge_bwd2(
    const float* __restrict__ ef, const float* __restrict__ sh, const float* __restrict__ rl,
    const float* __restrict__ uv, const float* __restrict__ nf, const float* __restrict__ gagg,
    const int* __restrict__ ei, const float* __restrict__ R1, const float* __restrict__ R2T,
    float* __restrict__ wbuf, float* __restrict__ gvec, int accum){
  int lane = threadIdx.x & 63;
  int wid = blockIdx.x*4 + (threadIdx.x >> 6);
  int nw  = gridDim.x*4;
  float r1c[8], r2tc[64];
  #pragma unroll
  for (int j = 0; j < 8; ++j)  r1c[j]  = R1[j*64 + lane];
  #pragma unroll
  for (int j = 0; j < 64; ++j) r2tc[j] = R2T[j*64 + lane];
  for (int e = wid; e < NE; e += nw){
    int s = __builtin_amdgcn_readfirstlane(ei[e]);
    int r = __builtin_amdgcn_readfirstlane(ei[NE+e]);
    float h = nf[(size_t)s*576 + lane];
    float w = wbuf[(size_t)e*64 + lane];
    float gm[9], shp[9];
    #pragma unroll
    for (int k = 0; k < 9; ++k){
      gm[k]  = gagg[(size_t)r*576 + (size_t)k*64 + lane]*(1.f/16.f);
      shp[k] = sh[(size_t)e*9 + k];
    }
    float S = 0.f;
    #pragma unroll
    for (int k = 0; k < 9; ++k) S = fmaf(gm[k], shp[k], S);
    float wh = w*h;
    float gshv[9];
    #pragma unroll
    for (int k = 0; k < 9; ++k){
      float v = gm[k]*wh;
      #pragma unroll
      for (int o = 32; o; o >>= 1) v += __shfl_xor(v, o, 64);
      gshv[k] = v;
    }
    // radial MLP backward (w*S -> gef)
    float gw = h*S;
    float g0 = 0.f, g1 = 0.f, g2 = 0.f, g3 = 0.f;
    #pragma unroll
    for (int j = 0; j < 64; j += 4){
      g0 = fmaf(rlane(gw, j  ), r2tc[j  ], g0);
      g1 = fmaf(rlane(gw, j+1), r2tc[j+1], g1);
      g2 = fmaf(rlane(gw, j+2), r2tc[j+2], g2);
      g3 = fmaf(rlane(gw, j+3), r2tc[j+3], g3);
    }
    float gsl = (g0+g1) + (g2+g3);
    float efv = ef[(size_t)e*8 + (lane & 7)];
    float a = 0.f;
    #pragma unroll
    for (int b = 0; b < 8; ++b) a = fmaf(rlane(efv, b), r1c[b], a);
    float sg = 1.f/(1.f + __expf(-a));
    float ga = gsl * sg * fmaf(a, 1.f - sg, 1.f);
    float gef[8];
    #pragma unroll
    for (int b = 0; b < 8; ++b){
      float v = ga*r1c[b];
      #pragma unroll
      for (int o = 32; o; o >>= 1) v += __shfl_xor(v, o, 64);
      gef[b] = v;
    }
    // geometry gradient (uniform across lanes)
    {
      float L = rl[e];
      float ux = uv[(size_t)e*3], uy = uv[(size_t)e*3+1], uz = uv[(size_t)e*3+2];
      float gr = 0.f;
      float ur = L*0.2f;
      if (ur < 1.f){
        float u2 = ur*ur, u4 = u2*u2, u5 = u4*ur;
        float fc = 1.f - 21.f*u5 + 35.f*u5*ur - 15.f*u5*u2;
        float omu = 1.f - ur;
        float dfc = -105.f*u4*omu*omu;
        float invr = 1.f/(L + 1e-9f);
        #pragma unroll
        for (int b = 0; b < 8; ++b){
          float nb = (float)(b+1);
          float arg = nb*PI_F*ur;
          float sn = sinf(arg), cs = cosf(arg);
          float bes = KBES*sn*invr;
          float dbes = KBES*(nb*PI_F*0.2f)*cs*invr - bes*invr;
          float defdr = dbes*fc + bes*dfc*0.2f;
          gr = fmaf(gef[b], defdr, gr);
        }
      }
      float gux = S3*gshv[1] + S15*(uy*gshv[4] + uz*gshv[7] + ux*gshv[8]);
      float guy = S3*gshv[2] + S15*(ux*gshv[4] + uz*gshv[5] - uy*gshv[8]);
      float guz = S3*gshv[3] + S15*(uy*gshv[5] + ux*gshv[7]) + 3.f*S5*uz*gshv[6];
      float dot = gux*ux + guy*uy + guz*uz;
      float invL = 1.f/L;
      float gvx = (gux - dot*ux)*invL + gr*ux;
      float gvy = (guy - dot*uy)*invL + gr*uy;
      float gvz = (guz - dot*uz)*invL + gr*uz;
      if (lane < 3){
        float comp = (lane==0) ? gvx : ((lane==1) ? gvy : gvz);
        size_t gi = (size_t)e*3 + lane;
        if (accum) gvec[gi] += comp; else gvec[gi] = comp;
      }
    }
    // gh staging (in-place)
    wbuf[(size_t)e*64 + lane] = w*S;
  }
}

// ================= v2: gh gather via sender CSR =================
__global__ __launch_bounds__(256) void k_ghgather(
    const float* __restrict__ ghc, const int* __restrict__ offs_, const int* __restrict__ lists,
    float* __restrict__ gnf){
  int lane = threadIdx.x & 63;
  int wid = blockIdx.x*4 + (threadIdx.x >> 6);
  int nw  = gridDim.x*4;
  for (int n = wid; n < NN; n += nw){
    int lo = offs_[n], hi = offs_[n+1];
    float acc = 0.f;
    for (int i = lo; i < hi; ++i){
      int e = __builtin_amdgcn_readfirstlane(lists[i]);
      acc += ghc[(size_t)e*64 + lane];
    }
    gnf[(size_t)n*576 + lane] += acc;
  }
}

// ================= v1 fallback edge kernels (proven) =================
__global__ __launch_bounds__(256) void k_edge_fwd(
    const float* __restrict__ ef, const float* __restrict__ sh, const float* __restrict__ nfprev,
    const int* __restrict__ ei, const float* __restrict__ R1, const float* __restrict__ R2,
    float* __restrict__ agg){
  __shared__ float R1s[512];
  __shared__ float R2s[4096];
  __shared__ float sa[4][64];
  for (int i = threadIdx.x; i < 512;  i += 256) R1s[i] = R1[i];
  for (int i = threadIdx.x; i < 4096; i += 256) R2s[i] = R2[i];
  __syncthreads();
  int lane = threadIdx.x & 63, wv = threadIdx.x >> 6;
  int ebase = blockIdx.x*32 + wv*8;
  for (int it = 0; it < 8; ++it){
    int e = ebase + it;
    const float* efp = ef + (size_t)e*8;
    float a = 0.f;
    #pragma unroll
    for (int b = 0; b < 8; ++b) a = fmaf(efp[b], R1s[b*64+lane], a);
    float sg = 1.f/(1.f + __expf(-a));
    sa[wv][lane] = a*sg;
    __builtin_amdgcn_wave_barrier();
    float w = 0.f;
    #pragma unroll
    for (int j = 0; j < 64; ++j) w = fmaf(sa[wv][j], R2s[j*64+lane], w);
    __builtin_amdgcn_wave_barrier();
    int s = ei[e], r = ei[NE + e];
    float h = nfprev[(size_t)s*576 + lane];
    float base = w*h*(1.f/16.f);
    const float* shp = sh + (size_t)e*9;
    float* ap = agg + (size_t)r*576 + lane;
    #pragma unroll
    for (int k = 0; k < 9; ++k) atomicAdd(ap + (size_t)k*64, base*shp[k]);
  }
}

__global__ __launch_bounds__(256) void k_edge_bwd(
    const float* __restrict__ ef, const float* __restrict__ sh, const float* __restrict__ rl,
    const float* __restrict__ uv, const float* __restrict__ nfprev, const float* __restrict__ gagg,
    const int* __restrict__ ei, const float* __restrict__ R1, const float* __restrict__ R2,
    const float* __restrict__ R2T, float* __restrict__ gnfprev, float* __restrict__ gvec,
    int need_gh, int accum){
  __shared__ float R1s[512];
  __shared__ float R2s[4096];
  __shared__ float R2Ts[4096];
  __shared__ float xch[4][64];
  for (int i = threadIdx.x; i < 512;  i += 256) R1s[i] = R1[i];
  for (int i = threadIdx.x; i < 4096; i += 256){ R2s[i] = R2[i]; R2Ts[i] = R2T[i]; }
  __syncthreads();
  int lane = threadIdx.x & 63, wv = threadIdx.x >> 6;
  int ebase = blockIdx.x*32 + wv*8;
  for (int it = 0; it < 8; ++it){
    int e = ebase + it;
    const float* efp = ef + (size_t)e*8;
    float a = 0.f;
    #pragma unroll
    for (int b = 0; b < 8; ++b) a = fmaf(efp[b], R1s[b*64+lane], a);
    float sg = 1.f/(1.f + __expf(-a));
    float sl = a*sg;
    xch[wv][lane] = sl;
    __builtin_amdgcn_wave_barrier();
    float w = 0.f;
    #pragma unroll
    for (int j = 0; j < 64; ++j) w = fmaf(xch[wv][j], R2s[j*64+lane], w);
    __builtin_amdgcn_wave_barrier();
    int s = ei[e], r = ei[NE + e];
    float h = nfprev[(size_t)s*576 + lane];
    const float* gp_ = gagg + (size_t)r*576 + lane;
    const float* shp = sh + (size_t)e*9;
    float gm[9], shv[9];
    #pragma unroll
    for (int k = 0; k < 9; ++k){ shv[k] = shp[k]; gm[k] = gp_[(size_t)k*64]*(1.f/16.f); }
    float S = 0.f;
    #pragma unroll
    for (int k = 0; k < 9; ++k) S = fmaf(gm[k], shv[k], S);
    float gw = h*S, gh = w*S;
    if (need_gh) atomicAdd(&gnfprev[(size_t)s*576 + lane], gh);
    float wh = w*h;
    float gshv[9];
    #pragma unroll
    for (int k = 0; k < 9; ++k){
      float v = gm[k]*wh;
      #pragma unroll
      for (int o = 32; o; o >>= 1) v += __shfl_xor(v, o, 64);
      gshv[k] = v;
    }
    xch[wv][lane] = gw;
    __builtin_amdgcn_wave_barrier();
    float gsl = 0.f;
    #pragma unroll
    for (int c2 = 0; c2 < 64; ++c2) gsl = fmaf(xch[wv][c2], R2Ts[c2*64+lane], gsl);
    __builtin_amdgcn_wave_barrier();
    float ga = gsl * sg * fmaf(a, 1.f - sg, 1.f);
    xch[wv][lane] = ga;
    __builtin_amdgcn_wave_barrier();
    float gefb = 0.f;
    if (lane < 8){
      #pragma unroll
      for (int j = 0; j < 64; ++j) gefb = fmaf(xch[wv][j], R1s[lane*64+j], gefb);
    }
    __builtin_amdgcn_wave_barrier();
    if (lane < 8) xch[wv][lane] = gefb;
    __builtin_amdgcn_wave_barrier();
    {
      float L = rl[e];
      float ux = uv[(size_t)e*3], uy = uv[(size_t)e*3+1], uz = uv[(size_t)e*3+2];
      float gr = 0.f;
      float ur = L*0.2f;
      if (ur < 1.f){
        float u2 = ur*ur, u4 = u2*u2, u5 = u4*ur;
        float fc = 1.f - 21.f*u5 + 35.f*u5*ur - 15.f*u5*u2;
        float omu = 1.f - ur;
        float dfc = -105.f*u4*omu*omu;
        float invr = 1.f/(L + 1e-9f);
        #pragma unroll
        for (int b = 0; b < 8; ++b){
          float nb = (float)(b+1);
          float arg = nb*PI_F*ur;
          float sn = sinf(arg), cs = cosf(arg);
          float bes = KBES*sn*invr;
          float dbes = KBES*(nb*PI_F*0.2f)*cs*invr - bes*invr;
          float defdr = dbes*fc + bes*dfc*0.2f;
          gr = fmaf(xch[wv][b], defdr, gr);
        }
      }
      float gux = S3*gshv[1] + S15*(uy*gshv[4] + uz*gshv[7] + ux*gshv[8]);
      float guy = S3*gshv[2] + S15*(ux*gshv[4] + uz*gshv[5] - uy*gshv[8]);
      float guz = S3*gshv[3] + S15*(uy*gshv[5] + ux*gshv[7]) + 3.f*S5*uz*gshv[6];
      float dot = gux*ux + guy*uy + guz*uz;
      float invL = 1.f/L;
      float gvx = (gux - dot*ux)*invL + gr*ux;
      float gvy = (guy - dot*uy)*invL + gr*uy;
      float gvz = (guz - dot*uz)*invL + gr*uz;
      if (lane < 3){
        float comp = (lane==0) ? gvx : ((lane==1) ? gvy : gvz);
        size_t gi = (size_t)e*3 + lane;
        if (accum) gvec[gi] += comp; else gvec[gi] = comp;
      }
    }
    __builtin_amdgcn_wave_barrier();
  }
}

// ---------- shared small kernels ----------
__global__ __launch_bounds__(256) void k_lin(const float* __restrict__ in, const float* __restrict__ W3,
                                             float* __restrict__ out, int accum){
  __shared__ float Wl[4096];
  int k = blockIdx.y;
  int l = (k==0) ? 0 : ((k<4) ? 1 : 2);
  const float* W = W3 + (size_t)l*4096;
  for (int i = threadIdx.x; i < 4096; i += 256) Wl[i] = W[i];
  __syncthreads();
  int d = threadIdx.x & 63, sub = threadIdx.x >> 6;
  int nbase = blockIdx.x*16;
  for (int i = 0; i < 4; ++i){
    int n = nbase + sub*4 + i;
    const float* inr = in + (size_t)n*576 + (size_t)k*64;
    float acc = 0.f;
    #pragma unroll
    for (int c = 0; c < 64; ++c) acc = fmaf(inr[c], Wl[c*64+d], acc);
    float* o = out + (size_t)n*576 + (size_t)k*64 + d;
    if (accum) *o += acc; else *o = acc;
  }
}

__global__ void k_poly(const float* __restrict__ msg, const float* __restrict__ wp, float* __restrict__ mp){
  int n = blockIdx.x, c = threadIdx.x;
  size_t base = (size_t)n*576 + c;
  float s0 = msg[base];
  float p = fmaf(fmaf(wp[c*3+2], s0, wp[c*3+1]), s0, wp[c*3+0]);
  #pragma unroll
  for (int k = 0; k < 9; ++k){
    size_t idx = base + (size_t)k*64;
    mp[idx] = msg[idx]*p;
  }
}

__global__ void k_edip(const float* __restrict__ nf, const float* __restrict__ we,
                       const float* __restrict__ wd, const int* __restrict__ batch,
                       float* __restrict__ Etg, float* __restrict__ adp, float* __restrict__ td){
  int n = blockIdx.x, c = threadIdx.x;
  int g = batch[n];
  float v = nf[(size_t)n*576 + c]*we[c];
  #pragma unroll
  for (int o = 32; o; o >>= 1) v += __shfl_xor(v, o, 64);
  if (c == 0) atomicAdd(&Etg[g], v);
  #pragma unroll
  for (int j = 0; j < 3; ++j){
    float dv = nf[(size_t)n*576 + (size_t)(j+1)*64 + c]*wd[c];
    #pragma unroll
    for (int o = 32; o; o >>= 1) dv += __shfl_xor(dv, o, 64);
    if (c == 0){ adp[n*3+j] += dv; atomicAdd(&td[g*3+j], dv); }
  }
}

__global__ void k_init_gnf(float* __restrict__ g, const float* __restrict__ we){
  int i = blockIdx.x*256 + threadIdx.x;
  if (i >= NN*576) return;
  int kd = i % 576;
  g[i] = (kd < 64) ? we[kd] : 0.f;
}

__global__ void k_add_we(float* __restrict__ g, const float* __restrict__ we){
  int i = blockIdx.x*256 + threadIdx.x;
  if (i >= NN*64) return;
  int n = i >> 6, d = i & 63;
  g[(size_t)n*576 + d] += we[d];
}

__global__ void k_poly_bwd(float* __restrict__ gmp, const float* __restrict__ msg,
                           const float* __restrict__ wp){
  int n = blockIdx.x, c = threadIdx.x;
  size_t base = (size_t)n*576 + c;
  float s0 = msg[base];
  float p1 = wp[c*3+1], p2 = wp[c*3+2];
  float poly = fmaf(fmaf(p2, s0, p1), s0, wp[c*3+0]);
  float gp = 0.f;
  #pragma unroll
  for (int k = 0; k < 9; ++k){
    size_t idx = base + (size_t)k*64;
    float g = gmp[idx];
    gp = fmaf(g, msg[idx], gp);
    gmp[idx] = g*poly;
  }
  gmp[base] += gp*fmaf(2.f*p2, s0, p1);
}

__global__ void k_gscatter(const float* __restrict__ gvec, const int* __restrict__ ei,
                           float* __restrict__ gpos){
  int e = blockIdx.x*256 + threadIdx.x;
  if (e >= NE) return;
  int s = ei[e], r = ei[NE + e];
  float gx = gvec[(size_t)e*3], gy = gvec[(size_t)e*3+1], gz = gvec[(size_t)e*3+2];
  atomicAdd(&gpos[s*3+0],  gx); atomicAdd(&gpos[s*3+1],  gy); atomicAdd(&gpos[s*3+2],  gz);
  atomicAdd(&gpos[r*3+0], -gx); atomicAdd(&gpos[r*3+1], -gy); atomicAdd(&gpos[r*3+2], -gz);
}

__global__ void k_charge(const float* __restrict__ q, const float* __restrict__ pos,
                         const int* __restrict__ batch, float* __restrict__ td){
  int n = blockIdx.x*256 + threadIdx.x;
  int lane = threadIdx.x & 63;
  bool valid = (n < NN);
  int g = valid ? batch[n] : -1;
  float px = 0.f, py = 0.f, pz = 0.f;
  if (valid){
    float qq = q[n];
    px = qq*pos[n*3+0]; py = qq*pos[n*3+1]; pz = qq*pos[n*3+2];
  }
  int g0 = __shfl(g, 0, 64), g63 = __shfl(g, 63, 64);
  if (g0 == g63 && g0 >= 0){
    #pragma unroll
    for (int o = 32; o; o >>= 1){
      px += __shfl_xor(px, o, 64); py += __shfl_xor(py, o, 64); pz += __shfl_xor(pz, o, 64);
    }
    if (lane == 0){
      atomicAdd(&td[g0*3+0], px); atomicAdd(&td[g0*3+1], py); atomicAdd(&td[g0*3+2], pz);
    }
  } else if (valid){
    atomicAdd(&td[g*3+0], px); atomicAdd(&td[g*3+1], py); atomicAdd(&td[g*3+2], pz);
  }
}

__global__ void k_writeout(const float* __restrict__ e0g, const float* __restrict__ Etg,
                           const float* __restrict__ td, const float* __restrict__ adp,
                           const float* __restrict__ gpos, void* __restrict__ outv,
                           const int* __restrict__ flag){
  int i = blockIdx.x*256 + threadIdx.x;
  const int total = NG + NG*3 + NN*3 + NG*3 + NN*3; // 60112
  if (i >= total) return;
  float v;
  if (i < 16){
    v = e0g[i] + Etg[i] + Etg[16+i];
  } else if (i < 64){
    int j = i - 16; int g = j/3, t = j - g*3;
    v = (t == 0) ? e0g[g] : Etg[(t-1)*16 + g];
  } else if (i < 64 + NN*3){
    v = -gpos[i-64];
  } else if (i < 64 + NN*3 + 48){
    v = td[i - (64 + NN*3)];
  } else {
    v = adp[i - (64 + NN*3 + 48)];
  }
  if (flag[0]) ((__hip_bfloat16*)outv)[i] = __float2bfloat16(v);
  else         ((float*)outv)[i] = v;
}

extern "C" void kernel_launch(void* const* d_in, const int* in_sizes, int n_in,
                              void* d_out, int out_size, void* d_ws, size_t ws_size,
                              hipStream_t stream) {
  if (ws_size < WS1_FLOATS*sizeof(float)) return;
  const bool v2 = (ws_size >= WS2_FLOATS*sizeof(float));
  const int* ei    = (const int*)d_in[14];
  const int* batch = (const int*)d_in[15];
  float* ws = (float*)d_ws;
  int* flag = (int*)(ws + O_FLAG);

  hipMemsetAsync(ws + OFF_ACC, 0, ACC_FLOATS*sizeof(float), stream);
  k_detect<<<1, 256, 0, stream>>>((const unsigned*)d_in[1], flag);

  auto load = [&](int idx, size_t off, int n){
    k_load<<<(n+255)/256, 256, 0, stream>>>(d_in[idx], ws+off, n, flag);
  };
  load(0,  OFF_PIN, NN*3);
  load(1,  OFF_ATT, NN*NZ);
  load(2,  OFF_CHG, NN);
  load(3,  OFF_SHF, NE*3);
  load(4,  O_WEMB,  NZ*64);
  load(5,  O_AE,    NZ);
  load(6,  O_R1,    NT*NBES*64);
  load(7,  O_R2,    NT*64*64);
  load(8,  O_WMIX,  NT*3*64*64);
  load(9,  O_WSC,   NT*3*64*64);
  load(10, O_WPOLY, NT*64*3);
  load(11, O_WPROD, NT*3*64*64);
  load(12, O_WE,    NT*64);
  load(13, O_WD,    NT*64);
  k_transpose64<<<(2*4096+255)/256, 256, 0, stream>>>(ws+O_R2,   ws+O_R2T,   2);
  k_transpose64<<<(6*4096+255)/256, 256, 0, stream>>>(ws+O_WMIX, ws+O_WMIXT, 6);
  k_transpose64<<<(6*4096+255)/256, 256, 0, stream>>>(ws+O_WSC,  ws+O_WSCT,  6);
  k_transpose64<<<(6*4096+255)/256, 256, 0, stream>>>(ws+O_WPROD,ws+O_WPRODT,6);

  k_geom<<<(NE+255)/256, 256, 0, stream>>>(ws+OFF_PIN, ws+OFF_SHF, ei, ws+OFF_SH, ws+OFF_EF, ws+OFF_RL, ws+OFF_UV);
  k_init_nodes<<<NN, 64, 0, stream>>>(ws+OFF_ATT, ws+O_WEMB, ws+O_AE, batch, ws+OFF_NF0, ws+O_E0G);

  const size_t NF[3]  = {OFF_NF0, OFF_NF1, OFF_NF2};
  const size_t MSG[2] = {OFF_MSG0, OFF_MSG1};
  dim3 ling(NN/16, 9);
  float* GA = ws + OFF_NF2;
  float* GB = ws + OFF_MSG1;

  if (v2){
    float* WBUF = ws + O_WBUF;
    int* offr  = (int*)(ws + O_OFFR);
    int* offs_ = (int*)(ws + O_OFFS);
    int* curr  = (int*)(ws + O_CURR);
    int* curs  = (int*)(ws + O_CURS);
    int* listr = (int*)(ws + O_LISTR);
    int* lists = (int*)(ws + O_LISTS);
    hipMemsetAsync(curr, 0, 2*NN*sizeof(int), stream);   // curr + curs contiguous
    k_csr_count<<<(NE+255)/256, 256, 0, stream>>>(ei, curr, curs);
    k_csr_scan<<<1, 256, 0, stream>>>(curr, curs, offr, offs_);
    k_csr_fill<<<(NE+255)/256, 256, 0, stream>>>(ei, curr, curs, listr, lists);

    // ---------- forward ----------
    for (int t = 0; t < NT; ++t){
      k_radial<<<1024, 256, 0, stream>>>(ws+OFF_EF, ws+O_R1 + (size_t)t*512, ws+O_R2 + (size_t)t*4096, WBUF);
      k_agg<<<640, 256, 0, stream>>>(WBUF, ws+OFF_SH, ws+NF[t], ei, offr, listr, ws+OFF_AGG);
      k_lin<<<ling, 256, 0, stream>>>(ws+OFF_AGG, ws+O_WMIX + (size_t)t*12288, ws+MSG[t], 0);
      k_lin<<<ling, 256, 0, stream>>>(ws+NF[t],   ws+O_WSC  + (size_t)t*12288, ws+NF[t+1], 0);
      k_poly<<<NN, 64, 0, stream>>>(ws+MSG[t], ws+O_WPOLY + (size_t)t*192, ws+OFF_AGG);
      k_lin<<<ling, 256, 0, stream>>>(ws+OFF_AGG, ws+O_WPROD + (size_t)t*12288, ws+NF[t+1], 1);
      k_edip<<<NN, 64, 0, stream>>>(ws+NF[t+1], ws+O_WE + (size_t)t*64, ws+O_WD + (size_t)t*64,
                                    batch, ws+O_ETG + (size_t)t*16, ws+O_ADP, ws+O_TD);
    }
    // ---------- backward ----------
    k_init_gnf<<<(NN*576+255)/256, 256, 0, stream>>>(GA, ws+O_WE + 64);
    { // t = 1  (WBUF still holds w1)
      int t = 1;
      k_lin<<<ling, 256, 0, stream>>>(GA, ws+O_WPRODT + (size_t)t*12288, ws+OFF_AGG, 0);
      k_poly_bwd<<<NN, 64, 0, stream>>>(ws+OFF_AGG, ws+MSG[t], ws+O_WPOLY + (size_t)t*192);
      k_lin<<<ling, 256, 0, stream>>>(GA, ws+O_WSCT + (size_t)t*12288, GB, 0);
      k_lin<<<ling, 256, 0, stream>>>(ws+OFF_AGG, ws+O_WMIXT + (size_t)t*12288, GA, 0);
      k_edge_bwd2<<<1024, 256, 0, stream>>>(ws+OFF_EF, ws+OFF_SH, ws+OFF_RL, ws+OFF_UV,
                                            ws+NF[t], GA, ei,
                                            ws+O_R1 + (size_t)t*512, ws+O_R2T + (size_t)t*4096,
                                            WBUF, ws+O_GVEC, 0);
      k_ghgather<<<640, 256, 0, stream>>>(WBUF, offs_, lists, GB);
      k_add_we<<<(NN*64+255)/256, 256, 0, stream>>>(GB, ws+O_WE);
    }
    { // t = 0  (recompute w0)
      int t = 0;
      k_radial<<<1024, 256, 0, stream>>>(ws+OFF_EF, ws+O_R1, ws+O_R2, WBUF);
      k_lin<<<ling, 256, 0, stream>>>(GB, ws+O_WPRODT + (size_t)t*12288, ws+OFF_AGG, 0);
      k_poly_bwd<<<NN, 64, 0, stream>>>(ws+OFF_AGG, ws+MSG[t], ws+O_WPOLY + (size_t)t*192);
      k_lin<<<ling, 256, 0, stream>>>(ws+OFF_AGG, ws+O_WMIXT + (size_t)t*12288, GA, 0);
      k_edge_bwd2<<<1024, 256, 0, stream>>>(ws+OFF_EF, ws+OFF_SH, ws+OFF_RL, ws+OFF_UV,
                                            ws+NF[t], GA, ei,
                                            ws+O_R1, ws+O_R2T,
                                            WBUF, ws+O_GVEC, 1);
    }
  } else {
    // ---------- v1 fallback ----------
    for (int t = 0; t < NT; ++t){
      hipMemsetAsync(ws + OFF_AGG, 0, NFSZ*sizeof(float), stream);
      k_edge_fwd<<<NE/32, 256, 0, stream>>>(ws+OFF_EF, ws+OFF_SH, ws+NF[t], ei,
                                            ws+O_R1 + (size_t)t*512, ws+O_R2 + (size_t)t*4096, ws+OFF_AGG);
      k_lin<<<ling, 256, 0, stream>>>(ws+OFF_AGG, ws+O_WMIX + (size_t)t*12288, ws+MSG[t], 0);
      k_lin<<<ling, 256, 0, stream>>>(ws+NF[t],   ws+O_WSC  + (size_t)t*12288, ws+NF[t+1], 0);
      k_poly<<<NN, 64, 0, stream>>>(ws+MSG[t], ws+O_WPOLY + (size_t)t*192, ws+OFF_AGG);
      k_lin<<<ling, 256, 0, stream>>>(ws+OFF_AGG, ws+O_WPROD + (size_t)t*12288, ws+NF[t+1], 1);
      k_edip<<<NN, 64, 0, stream>>>(ws+NF[t+1], ws+O_WE + (size_t)t*64, ws+O_WD + (size_t)t*64,
                                    batch, ws+O_ETG + (size_t)t*16, ws+O_ADP, ws+O_TD);
    }
    k_init_gnf<<<(NN*576+255)/256, 256, 0, stream>>>(GA, ws+O_WE + 64);
    {
      int t = 1;
      k_lin<<<ling, 256, 0, stream>>>(GA, ws+O_WPRODT + (size_t)t*12288, ws+OFF_AGG, 0);
      k_poly_bwd<<<NN, 64, 0, stream>>>(ws+OFF_AGG, ws+MSG[t], ws+O_WPOLY + (size_t)t*192);
      k_lin<<<ling, 256, 0, stream>>>(GA, ws+O_WSCT + (size_t)t*12288, GB, 0);
      k_lin<<<ling, 256, 0, stream>>>(ws+OFF_AGG, ws+O_WMIXT + (size_t)t*12288, GA, 0);
      k_edge_bwd<<<NE/32, 256, 0, stream>>>(ws+OFF_EF, ws+OFF_SH, ws+OFF_RL, ws+OFF_UV,
                                            ws+NF[t], GA, ei,
                                            ws+O_R1 + (size_t)t*512, ws+O_R2 + (size_t)t*4096,
                                            ws+O_R2T + (size_t)t*4096, GB, ws+O_GVEC, 1, 0);
      k_add_we<<<(NN*64+255)/256, 256, 0, stream>>>(GB, ws+O_WE);
    }
    {
      int t = 0;
      k_lin<<<ling, 256, 0, stream>>>(GB, ws+O_WPRODT + (size_t)t*12288, ws+OFF_AGG, 0);
      k_poly_bwd<<<NN, 64, 0, stream>>>(ws+OFF_AGG, ws+MSG[t], ws+O_WPOLY + (size_t)t*192);
      k_lin<<<ling, 256, 0, stream>>>(ws+OFF_AGG, ws+O_WMIXT + (size_t)t*12288, GA, 0);
      k_edge_bwd<<<NE/32, 256, 0, stream>>>(ws+OFF_EF, ws+OFF_SH, ws+OFF_RL, ws+OFF_UV,
                                            ws+NF[t], GA, ei,
                                            ws+O_R1, ws+O_R2 ,
                                            ws+O_R2T, GB, ws+O_GVEC, 0, 1);
    }
  }

  k_gscatter<<<(NE+255)/256, 256, 0, stream>>>(ws+O_GVEC, ei, ws+O_GPOS);
  k_charge<<<(NN+255)/256, 256, 0, stream>>>(ws+OFF_CHG, ws+OFF_PIN, batch, ws+O_TD);
  k_writeout<<<(60112+255)/256, 256, 0, stream>>>(ws+O_E0G, ws+O_ETG, ws+O_TD, ws+O_ADP, ws+O_GPOS, d_out, flag);
}

// Round 5
// 1961.498 us; speedup vs baseline: 1.6751x; 1.3523x over previous
//
#include <hip/hip_runtime.h>
#include <hip/hip_bf16.h>

#define NN 10000
#define NE 160000
#define NZ 10
#define NC 64
#define NBES 8
#define NG 16
#define NT 2

static constexpr float PI_F  = 3.14159265358979323846f;
static constexpr float KBES  = 0.63245553203367587f;  // sqrt(2/5)
static constexpr float S3    = 1.73205080756887729f;
static constexpr float S5    = 2.23606797749978969f;
static constexpr float S15   = 3.87298334620741688f;

// ---- workspace layout (float offsets) ----
static constexpr size_t OFF_SH   = 0;
static constexpr size_t OFF_EF   = OFF_SH  + (size_t)NE*9;
static constexpr size_t OFF_RL   = OFF_EF  + (size_t)NE*8;
static constexpr size_t OFF_UV   = OFF_RL  + (size_t)NE;
static constexpr size_t OFF_PIN  = OFF_UV  + (size_t)NE*3;
static constexpr size_t OFF_ATT  = OFF_PIN + (size_t)NN*3;
static constexpr size_t OFF_CHG  = OFF_ATT + (size_t)NN*NZ;
static constexpr size_t OFF_SHF  = OFF_CHG + (size_t)NN;
static constexpr size_t NFSZ     = (size_t)NN*576;
static constexpr size_t OFF_NF0  = OFF_SHF + (size_t)NE*3;
static constexpr size_t OFF_NF1  = OFF_NF0 + NFSZ;
static constexpr size_t OFF_NF2  = OFF_NF1 + NFSZ;   // aliased as gnf "A" in bwd
static constexpr size_t OFF_MSG0 = OFF_NF2 + NFSZ;
static constexpr size_t OFF_MSG1 = OFF_MSG0+ NFSZ;   // aliased as gnf "B" in bwd
static constexpr size_t OFF_AGG  = OFF_MSG1+ NFSZ;
static constexpr size_t OFF_W    = OFF_AGG + NFSZ;
static constexpr size_t O_WEMB   = OFF_W;
static constexpr size_t O_AE     = O_WEMB + 640;
static constexpr size_t O_R1     = O_AE   + 16;
static constexpr size_t O_R2     = O_R1   + 1024;
static constexpr size_t O_R2T    = O_R2   + 8192;
static constexpr size_t O_WMIX   = O_R2T  + 8192;
static constexpr size_t O_WMIXT  = O_WMIX + 24576;
static constexpr size_t O_WSC    = O_WMIXT+ 24576;
static constexpr size_t O_WSCT   = O_WSC  + 24576;
static constexpr size_t O_WPROD  = O_WSCT + 24576;
static constexpr size_t O_WPRODT = O_WPROD+ 24576;
static constexpr size_t O_WPOLY  = O_WPRODT+24576;
static constexpr size_t O_WE     = O_WPOLY+ 384;
static constexpr size_t O_WD     = O_WE   + 128;
static constexpr size_t OFF_ACC  = O_WD   + 128;
static constexpr size_t O_E0G    = OFF_ACC;
static constexpr size_t O_ETG    = O_E0G + 16;
static constexpr size_t O_TD     = O_ETG + 32;
static constexpr size_t O_ADP    = O_TD  + 48;
static constexpr size_t O_GPOS   = O_ADP + (size_t)NN*3;
static constexpr size_t O_GVEC   = O_GPOS+ (size_t)NN*3;     // per-edge dE/dvec (NOT zeroed)
static constexpr size_t ACC_FLOATS = O_GVEC - OFF_ACC;
static constexpr size_t O_FLAG   = O_GVEC + (size_t)NE*3;
static constexpr size_t WS1_FLOATS = O_FLAG + 4;
// ---- v2 additions ----
static constexpr size_t O_WBUF  = WS1_FLOATS;                // E*64 radial weights / gh staging
static constexpr size_t O_OFFR  = O_WBUF + (size_t)NE*64;    // ints from here
static constexpr size_t O_OFFS  = O_OFFR + (NN+1);
static constexpr size_t O_CURR  = O_OFFS + (NN+1);
static constexpr size_t O_CURS  = O_CURR + NN;
static constexpr size_t O_LISTR = O_CURS + NN;
static constexpr size_t O_LISTS = O_LISTR + (size_t)NE;
static constexpr size_t WS2_FLOATS = O_LISTS + (size_t)NE;   // ~201 MB
// ---- v3 addition: per-edge radial-derivative table ----
static constexpr size_t O_EFD   = WS2_FLOATS;
static constexpr size_t WS3_FLOATS = O_EFD + (size_t)NE*8;   // ~206 MB

__device__ __forceinline__ float rlane(float v, int l){
  return __int_as_float(__builtin_amdgcn_readlane(__float_as_int(v), l));
}

__device__ __forceinline__ void edge_defdr(float L, float* dd){
  float ur = L*0.2f;
  if (ur < 1.f){
    float u2=ur*ur, u4=u2*u2, u5=u4*ur;
    float fc = 1.f - 21.f*u5 + 35.f*u5*ur - 15.f*u5*u2;
    float omu = 1.f - ur;
    float dfc = -105.f*u4*omu*omu;
    float invr = 1.f/(L + 1e-9f);
    #pragma unroll
    for (int b = 0; b < 8; ++b){
      float nb = (float)(b+1);
      float arg = nb*PI_F*ur;
      float sn = sinf(arg), cs = cosf(arg);
      float bes = KBES*sn*invr;
      float dbes = KBES*(nb*PI_F*0.2f)*cs*invr - bes*invr;
      dd[b] = dbes*fc + bes*dfc*0.2f;
    }
  } else {
    #pragma unroll
    for (int b = 0; b < 8; ++b) dd[b] = 0.f;
  }
}

// ---------- dtype detection ----------
__global__ void k_detect(const unsigned* __restrict__ raw, int* __restrict__ flag){
  __shared__ int found;
  if (threadIdx.x == 0) found = 0;
  __syncthreads();
  for (int i = threadIdx.x; i < 4096; i += 256){
    unsigned w = raw[i];
    if (w == 0x00003F80u || w == 0x3F803F80u) found = 1;
  }
  __syncthreads();
  if (threadIdx.x == 0) flag[0] = found;
}

// ---------- fused loader: all 14 float inputs -> f32 workspace ----------
static constexpr int LD_CNT[14] = {NN*3, NN*NZ, NN, NE*3, NZ*64, NZ, NT*NBES*64, NT*64*64,
                                   NT*3*64*64, NT*3*64*64, NT*64*3, NT*3*64*64, NT*64, NT*64};
static constexpr int LD_TOTAL = NN*3 + NN*NZ + NN + NE*3 + NZ*64 + NZ + NT*NBES*64 + NT*64*64
                              + 3*(NT*3*64*64) + NT*64*3 + 4*(NT*64) - NT*64*2; // 704234
__global__ __launch_bounds__(256) void k_load_all(
    const void* s0, const void* s1, const void* s2, const void* s3, const void* s4,
    const void* s5, const void* s6, const void* s7, const void* s8, const void* s9,
    const void* s10, const void* s11, const void* s12, const void* s13,
    float* __restrict__ ws, const int* __restrict__ flag){
  const void* srcs[14] = {s0,s1,s2,s3,s4,s5,s6,s7,s8,s9,s10,s11,s12,s13};
  const size_t dsts[14] = {OFF_PIN, OFF_ATT, OFF_CHG, OFF_SHF, O_WEMB, O_AE, O_R1, O_R2,
                           O_WMIX, O_WSC, O_WPOLY, O_WPROD, O_WE, O_WD};
  int i = blockIdx.x*256 + threadIdx.x;
  int seg = -1, off = i;
  #pragma unroll
  for (int j = 0; j < 14; ++j){
    if (seg < 0){
      if (off < LD_CNT[j]) seg = j;
      else off -= LD_CNT[j];
    }
  }
  if (seg < 0) return;
  float v = flag[0] ? __bfloat162float(((const __hip_bfloat16*)srcs[seg])[off])
                    : ((const float*)srcs[seg])[off];
  ws[dsts[seg] + off] = v;
}

// ---------- fused transposes: 20 64x64 matrices ----------
__global__ void k_transpose_all(float* __restrict__ ws){
  const size_t srcs[4] = {O_R2, O_WMIX, O_WSC, O_WPROD};
  const size_t dsts[4] = {O_R2T, O_WMIXT, O_WSCT, O_WPRODT};
  const int cnts[4] = {2, 6, 6, 6};
  int i = blockIdx.x*256 + threadIdx.x;
  if (i >= 20*4096) return;
  int mm = i >> 12, r = (i >> 6) & 63, c = i & 63;
  int grp = 0, m = mm;
  #pragma unroll
  for (int j = 0; j < 4; ++j){ if (m >= cnts[j] && j < 3){ m -= cnts[j]; grp = j+1; } }
  ws[dsts[grp] + (size_t)m*4096 + (size_t)c*64 + r] =
      ws[srcs[grp] + (size_t)m*4096 + (size_t)r*64 + c];
}

// ---------- edge geometry (+ radial derivative table) ----------
__global__ void k_geom(const float* __restrict__ pos, const float* __restrict__ shifts,
                       const int* __restrict__ ei, float* __restrict__ sh, float* __restrict__ ef,
                       float* __restrict__ rl, float* __restrict__ uv, float* __restrict__ efd){
  int e = blockIdx.x*256 + threadIdx.x;
  if (e >= NE) return;
  int s = ei[e], r = ei[NE + e];
  float vx = pos[s*3+0] - pos[r*3+0] + shifts[(size_t)e*3+0];
  float vy = pos[s*3+1] - pos[r*3+1] + shifts[(size_t)e*3+1];
  float vz = pos[s*3+2] - pos[r*3+2] + shifts[(size_t)e*3+2];
  float L = sqrtf(vx*vx + vy*vy + vz*vz + 1e-12f);
  float inv = 1.f / L;
  float x = vx*inv, y = vy*inv, z = vz*inv;
  float* shp = sh + (size_t)e*9;
  shp[0] = 1.f;     shp[1] = S3*x;    shp[2] = S3*y;   shp[3] = S3*z;
  shp[4] = S15*x*y; shp[5] = S15*y*z; shp[6] = 0.5f*S5*(3.f*z*z - 1.f);
  shp[7] = S15*x*z; shp[8] = 0.5f*S15*(x*x - y*y);
  rl[e] = L;
  uv[(size_t)e*3+0] = x; uv[(size_t)e*3+1] = y; uv[(size_t)e*3+2] = z;
  float ur = L * 0.2f;
  float fc = 0.f;
  if (ur < 1.f){
    float u2 = ur*ur, u4 = u2*u2, u5 = u4*ur;
    fc = 1.f - 21.f*u5 + 35.f*u5*ur - 15.f*u5*u2;
  }
  float invr = 1.f / (L + 1e-9f);
  float* efp = ef + (size_t)e*8;
  #pragma unroll
  for (int b = 0; b < 8; ++b){
    float arg = (float)(b+1) * PI_F * ur;
    efp[b] = KBES * sinf(arg) * invr * fc;
  }
  if (efd){
    float dd[8];
    edge_defdr(L, dd);
    #pragma unroll
    for (int b = 0; b < 8; ++b) efd[(size_t)e*8+b] = dd[b];
  }
}

// ---------- node init ----------
__global__ __launch_bounds__(256) void k_init_nodes(
    const float* __restrict__ attrs, const float* __restrict__ Wemb,
    const float* __restrict__ ae, const int* __restrict__ batch,
    float* __restrict__ nf0, float* __restrict__ e0g){
  int lane = threadIdx.x & 63;
  int n = blockIdx.x*4 + (threadIdx.x >> 6);
  if (n >= NN) return;
  float acc = 0.f;
  #pragma unroll
  for (int z = 0; z < NZ; ++z) acc = fmaf(attrs[(size_t)n*NZ+z], Wemb[z*64+lane], acc);
  size_t base = (size_t)n*576;
  nf0[base + lane] = acc;
  #pragma unroll
  for (int k = 1; k < 9; ++k) nf0[base + (size_t)k*64 + lane] = 0.f;
  if (lane == 0){
    float e = 0.f;
    #pragma unroll
    for (int z = 0; z < NZ; ++z) e = fmaf(attrs[(size_t)n*NZ+z], ae[z], e);
    atomicAdd(&e0g[batch[n]], e);
  }
}

// ================= CSR construction =================
__global__ void k_csr_count(const int* __restrict__ ei, int* __restrict__ cntr, int* __restrict__ cnts){
  int e = blockIdx.x*256 + threadIdx.x;
  if (e >= NE) return;
  atomicAdd(&cntr[ei[NE+e]], 1);
  atomicAdd(&cnts[ei[e]], 1);
}

__global__ void k_csr_scan(int* __restrict__ cntr, int* __restrict__ cnts,
                           int* __restrict__ offr, int* __restrict__ offs_){
  __shared__ int part[256];
  for (int q = 0; q < 2; ++q){
    int* c   = q ? cnts  : cntr;
    int* off = q ? offs_ : offr;
    const int chunk = (NN + 255)/256;
    int lo = threadIdx.x*chunk, hi = lo+chunk; if (hi > NN) hi = NN; if (lo > NN) lo = NN;
    int s = 0;
    for (int i = lo; i < hi; ++i) s += c[i];
    part[threadIdx.x] = s;
    __syncthreads();
    for (int o = 1; o < 256; o <<= 1){
      int v = (threadIdx.x >= o) ? part[threadIdx.x-o] : 0;
      __syncthreads();
      part[threadIdx.x] += v;
      __syncthreads();
    }
    int run = (threadIdx.x == 0) ? 0 : part[threadIdx.x-1];
    for (int i = lo; i < hi; ++i){
      int ci = c[i];
      off[i] = run; c[i] = run;
      run += ci;
    }
    if (threadIdx.x == 255) off[NN] = run;
    __syncthreads();
  }
}

__global__ void k_csr_fill(const int* __restrict__ ei, int* __restrict__ curr, int* __restrict__ curs,
                           int* __restrict__ listr, int* __restrict__ lists){
  int e = blockIdx.x*256 + threadIdx.x;
  if (e >= NE) return;
  int pr = atomicAdd(&curr[ei[NE+e]], 1); listr[pr] = e;
  int ps = atomicAdd(&curs[ei[e]], 1);    lists[ps] = e;
}

// ================= radial MLP (VGPR-resident) =================
__global__ __launch_bounds__(256) void k_radial(
    const float* __restrict__ ef, const float* __restrict__ R1, const float* __restrict__ R2,
    float* __restrict__ wbuf){
  int lane = threadIdx.x & 63;
  int wid = blockIdx.x*4 + (threadIdx.x >> 6);
  int nw  = gridDim.x*4;
  float r1c[8], r2c[64];
  #pragma unroll
  for (int j = 0; j < 8; ++j)  r1c[j] = R1[j*64 + lane];
  #pragma unroll
  for (int j = 0; j < 64; ++j) r2c[j] = R2[j*64 + lane];
  for (int e = wid; e < NE; e += nw){
    float efv = ef[(size_t)e*8 + (lane & 7)];
    float a = 0.f;
    #pragma unroll
    for (int b = 0; b < 8; ++b) a = fmaf(rlane(efv, b), r1c[b], a);
    float sg = 1.f/(1.f + __expf(-a));
    float sl = a*sg;
    float w0 = 0.f, w1 = 0.f, w2 = 0.f, w3 = 0.f;
    #pragma unroll
    for (int j = 0; j < 64; j += 4){
      w0 = fmaf(rlane(sl, j  ), r2c[j  ], w0);
      w1 = fmaf(rlane(sl, j+1), r2c[j+1], w1);
      w2 = fmaf(rlane(sl, j+2), r2c[j+2], w2);
      w3 = fmaf(rlane(sl, j+3), r2c[j+3], w3);
    }
    wbuf[(size_t)e*64 + lane] = (w0+w1) + (w2+w3);
  }
}

// ================= atomic-free aggregation via receiver CSR =================
__global__ __launch_bounds__(256) void k_agg(
    const float* __restrict__ wbuf, const float* __restrict__ sh, const float* __restrict__ nf,
    const int* __restrict__ ei, const int* __restrict__ offr, const int* __restrict__ listr,
    float* __restrict__ agg){
  int lane = threadIdx.x & 63;
  int wid = blockIdx.x*4 + (threadIdx.x >> 6);
  int nw  = gridDim.x*4;
  for (int n = wid; n < NN; n += nw){
    int lo = offr[n], hi = offr[n+1];
    float acc[9];
    #pragma unroll
    for (int k = 0; k < 9; ++k) acc[k] = 0.f;
    for (int i = lo; i < hi; ++i){
      int e = __builtin_amdgcn_readfirstlane(listr[i]);
      int s = __builtin_amdgcn_readfirstlane(ei[e]);
      float wh = wbuf[(size_t)e*64 + lane] * nf[(size_t)s*576 + lane];
      const float* shp = sh + (size_t)e*9;
      #pragma unroll
      for (int k = 0; k < 9; ++k) acc[k] = fmaf(wh, shp[k], acc[k]);
    }
    size_t ob = (size_t)n*576 + lane;
    #pragma unroll
    for (int k = 0; k < 9; ++k) agg[ob + (size_t)k*64] = acc[k]*(1.f/16.f);
  }
}

// ================= per-l linear, readlane matvec =================
// flags: bit0 = accumulate into out, bit1 = poly-gate input (needs wp)
__global__ __launch_bounds__(256) void k_lin2(
    const float* __restrict__ in, const float* __restrict__ W3, const float* __restrict__ wp,
    float* __restrict__ out, int flags){
  int k = blockIdx.y;
  int l = (k==0) ? 0 : ((k<4) ? 1 : 2);
  const float* W = W3 + (size_t)l*4096;
  int lane = threadIdx.x & 63;
  float wcol[64];
  #pragma unroll
  for (int j = 0; j < 64; ++j) wcol[j] = W[j*64 + lane];
  float p0 = 0.f, p1 = 0.f, p2 = 0.f;
  if (flags & 2){ p0 = wp[lane*3]; p1 = wp[lane*3+1]; p2 = wp[lane*3+2]; }
  int wid = blockIdx.x*4 + (threadIdx.x >> 6);
  int nw  = gridDim.x*4;
  for (int n = wid; n < NN; n += nw){
    size_t base = (size_t)n*576;
    float x = in[base + (size_t)k*64 + lane];
    if (flags & 2){
      float s0 = in[base + lane];
      x *= fmaf(fmaf(p2, s0, p1), s0, p0);
    }
    float a0 = 0.f, a1 = 0.f, a2 = 0.f, a3 = 0.f;
    #pragma unroll
    for (int j = 0; j < 64; j += 4){
      a0 = fmaf(rlane(x, j  ), wcol[j  ], a0);
      a1 = fmaf(rlane(x, j+1), wcol[j+1], a1);
      a2 = fmaf(rlane(x, j+2), wcol[j+2], a2);
      a3 = fmaf(rlane(x, j+3), wcol[j+3], a3);
    }
    float acc = (a0+a1) + (a2+a3);
    float* o = out + base + (size_t)k*64 + lane;
    if (flags & 1) *o += acc; else *o = acc;
  }
}

// ================= per-receiver backward edge kernel =================
__global__ __launch_bounds__(256) void k_edge_bwd3(
    const float* __restrict__ ef, const float* __restrict__ efd, const float* __restrict__ sh,
    const float* __restrict__ rl, const float* __restrict__ uv,
    const float* __restrict__ nf, const float* __restrict__ gagg, const int* __restrict__ ei,
    const float* __restrict__ R1, const float* __restrict__ R2T,
    const int* __restrict__ offr, const int* __restrict__ listr,
    float* __restrict__ wbuf, float* __restrict__ gvec, int need_gh, int accum){
  int lane = threadIdx.x & 63;
  int wid = blockIdx.x*4 + (threadIdx.x >> 6);
  int nw  = gridDim.x*4;
  float r1c[8], r2tc[64];
  #pragma unroll
  for (int j = 0; j < 8; ++j)  r1c[j]  = R1[j*64 + lane];
  #pragma unroll
  for (int j = 0; j < 64; ++j) r2tc[j] = R2T[j*64 + lane];
  for (int n = wid; n < NN; n += nw){
    float gm[9];
    #pragma unroll
    for (int k = 0; k < 9; ++k) gm[k] = gagg[(size_t)n*576 + (size_t)k*64 + lane]*(1.f/16.f);
    int lo = offr[n], hi = offr[n+1];
    for (int i = lo; i < hi; ++i){
      int e = __builtin_amdgcn_readfirstlane(listr[i]);
      int s = __builtin_amdgcn_readfirstlane(ei[e]);
      float h = nf[(size_t)s*576 + lane];
      float w = wbuf[(size_t)e*64 + lane];
      float shp[9];
      #pragma unroll
      for (int k = 0; k < 9; ++k) shp[k] = sh[(size_t)e*9 + k];
      float S = 0.f;
      #pragma unroll
      for (int k = 0; k < 9; ++k) S = fmaf(gm[k], shp[k], S);
      float gw = h*S;
      // radial MLP backward
      float g0 = 0.f, g1 = 0.f, g2 = 0.f, g3 = 0.f;
      #pragma unroll
      for (int j = 0; j < 64; j += 4){
        g0 = fmaf(rlane(gw, j  ), r2tc[j  ], g0);
        g1 = fmaf(rlane(gw, j+1), r2tc[j+1], g1);
        g2 = fmaf(rlane(gw, j+2), r2tc[j+2], g2);
        g3 = fmaf(rlane(gw, j+3), r2tc[j+3], g3);
      }
      float gsl = (g0+g1) + (g2+g3);
      float efv = ef[(size_t)e*8 + (lane & 7)];
      float a = 0.f;
      #pragma unroll
      for (int b = 0; b < 8; ++b) a = fmaf(rlane(efv, b), r1c[b], a);
      float sg = 1.f/(1.f + __expf(-a));
      float ga = gsl * sg * fmaf(a, 1.f - sg, 1.f);
      // per-lane geometry partials (defdr uniform per edge)
      float dd[8];
      if (efd){
        #pragma unroll
        for (int b = 0; b < 8; ++b) dd[b] = efd[(size_t)e*8 + b];
      } else {
        edge_defdr(rl[e], dd);
      }
      float t = 0.f;
      #pragma unroll
      for (int b = 0; b < 8; ++b) t = fmaf(r1c[b], dd[b], t);
      float ux = uv[(size_t)e*3], uy = uv[(size_t)e*3+1], uz = uv[(size_t)e*3+2];
      float wh = w*h;
      float px = S3*gm[1] + S15*(uy*gm[4] + uz*gm[7] + ux*gm[8]);
      float py = S3*gm[2] + S15*(ux*gm[4] + uz*gm[5] - uy*gm[8]);
      float pz = S3*gm[3] + S15*(uy*gm[5] + ux*gm[7]) + 3.f*S5*uz*gm[6];
      float rx = wh*px, ry = wh*py, rz = wh*pz, rr = ga*t;
      #pragma unroll
      for (int o = 32; o; o >>= 1){
        rx += __shfl_xor(rx, o, 64); ry += __shfl_xor(ry, o, 64);
        rz += __shfl_xor(rz, o, 64); rr += __shfl_xor(rr, o, 64);
      }
      float L = rl[e];
      float dot = rx*ux + ry*uy + rz*uz;
      float invL = 1.f/L;
      float gvx = (rx - dot*ux)*invL + rr*ux;
      float gvy = (ry - dot*uy)*invL + rr*uy;
      float gvz = (rz - dot*uz)*invL + rr*uz;
      if (lane < 3){
        float comp = (lane==0) ? gvx : ((lane==1) ? gvy : gvz);
        size_t gi = (size_t)e*3 + lane;
        if (accum) gvec[gi] += comp; else gvec[gi] = comp;
      }
      if (need_gh) wbuf[(size_t)e*64 + lane] = w*S;   // gh staging (w consumed above)
    }
  }
}

// ================= gh gather via sender CSR =================
__global__ __launch_bounds__(256) void k_ghgather(
    const float* __restrict__ ghc, const int* __restrict__ offs_, const int* __restrict__ lists,
    float* __restrict__ gnf){
  int lane = threadIdx.x & 63;
  int wid = blockIdx.x*4 + (threadIdx.x >> 6);
  int nw  = gridDim.x*4;
  for (int n = wid; n < NN; n += nw){
    int lo = offs_[n], hi = offs_[n+1];
    float acc = 0.f;
    for (int i = lo; i < hi; ++i){
      int e = __builtin_amdgcn_readfirstlane(lists[i]);
      acc += ghc[(size_t)e*64 + lane];
    }
    gnf[(size_t)n*576 + lane] += acc;
  }
}

// ---------- small kernels ----------
__global__ __launch_bounds__(256) void k_edip(
    const float* __restrict__ nf, const float* __restrict__ we,
    const float* __restrict__ wd, const int* __restrict__ batch,
    float* __restrict__ Etg, float* __restrict__ adp, float* __restrict__ td){
  int lane = threadIdx.x & 63;
  int n = blockIdx.x*4 + (threadIdx.x >> 6);
  if (n >= NN) return;
  int g = batch[n];
  float v = nf[(size_t)n*576 + lane]*we[lane];
  #pragma unroll
  for (int o = 32; o; o >>= 1) v += __shfl_xor(v, o, 64);
  if (lane == 0) atomicAdd(&Etg[g], v);
  #pragma unroll
  for (int j = 0; j < 3; ++j){
    float dv = nf[(size_t)n*576 + (size_t)(j+1)*64 + lane]*wd[lane];
    #pragma unroll
    for (int o = 32; o; o >>= 1) dv += __shfl_xor(dv, o, 64);
    if (lane == 0){ adp[n*3+j] += dv; atomicAdd(&td[g*3+j], dv); }
  }
}

__global__ void k_init_gnf(float* __restrict__ g, const float* __restrict__ we){
  int i = blockIdx.x*256 + threadIdx.x;
  if (i >= NN*576) return;
  int kd = i % 576;
  g[i] = (kd < 64) ? we[kd] : 0.f;
}

__global__ void k_add_we(float* __restrict__ g, const float* __restrict__ we){
  int i = blockIdx.x*256 + threadIdx.x;
  if (i >= NN*64) return;
  int n = i >> 6, d = i & 63;
  g[(size_t)n*576 + d] += we[d];
}

__global__ __launch_bounds__(256) void k_poly_bwd(
    float* __restrict__ gmp, const float* __restrict__ msg, const float* __restrict__ wp){
  int lane = threadIdx.x & 63;
  int n = blockIdx.x*4 + (threadIdx.x >> 6);
  if (n >= NN) return;
  size_t base = (size_t)n*576 + lane;
  float s0 = msg[base];
  float p1 = wp[lane*3+1], p2 = wp[lane*3+2];
  float poly = fmaf(fmaf(p2, s0, p1), s0, wp[lane*3+0]);
  float gp = 0.f;
  #pragma unroll
  for (int k = 0; k < 9; ++k){
    size_t idx = base + (size_t)k*64;
    float g = gmp[idx];
    gp = fmaf(g, msg[idx], gp);
    gmp[idx] = g*poly;
  }
  gmp[base] += gp*fmaf(2.f*p2, s0, p1);
}

// ---------- CSR-based force assembly (no atomics) ----------
__global__ void k_gpos(const float* __restrict__ gvec,
                       const int* __restrict__ offr, const int* __restrict__ listr,
                       const int* __restrict__ offs_, const int* __restrict__ lists,
                       float* __restrict__ gpos){
  int n = blockIdx.x*256 + threadIdx.x;
  if (n >= NN) return;
  float ax = 0.f, ay = 0.f, az = 0.f;
  for (int i = offs_[n]; i < offs_[n+1]; ++i){
    int e = lists[i];
    ax += gvec[(size_t)e*3]; ay += gvec[(size_t)e*3+1]; az += gvec[(size_t)e*3+2];
  }
  for (int i = offr[n]; i < offr[n+1]; ++i){
    int e = listr[i];
    ax -= gvec[(size_t)e*3]; ay -= gvec[(size_t)e*3+1]; az -= gvec[(size_t)e*3+2];
  }
  gpos[n*3+0] = ax; gpos[n*3+1] = ay; gpos[n*3+2] = az;
}

__global__ void k_charge(const float* __restrict__ q, const float* __restrict__ pos,
                         const int* __restrict__ batch, float* __restrict__ td){
  int n = blockIdx.x*256 + threadIdx.x;
  int lane = threadIdx.x & 63;
  bool valid = (n < NN);
  int g = valid ? batch[n] : -1;
  float px = 0.f, py = 0.f, pz = 0.f;
  if (valid){
    float qq = q[n];
    px = qq*pos[n*3+0]; py = qq*pos[n*3+1]; pz = qq*pos[n*3+2];
  }
  int g0 = __shfl(g, 0, 64), g63 = __shfl(g, 63, 64);
  if (g0 == g63 && g0 >= 0){
    #pragma unroll
    for (int o = 32; o; o >>= 1){
      px += __shfl_xor(px, o, 64); py += __shfl_xor(py, o, 64); pz += __shfl_xor(pz, o, 64);
    }
    if (lane == 0){
      atomicAdd(&td[g0*3+0], px); atomicAdd(&td[g0*3+1], py); atomicAdd(&td[g0*3+2], pz);
    }
  } else if (valid){
    atomicAdd(&td[g*3+0], px); atomicAdd(&td[g*3+1], py); atomicAdd(&td[g*3+2], pz);
  }
}

__global__ void k_writeout(const float* __restrict__ e0g, const float* __restrict__ Etg,
                           const float* __restrict__ td, const float* __restrict__ adp,
                           const float* __restrict__ gpos, void* __restrict__ outv,
                           const int* __restrict__ flag){
  int i = blockIdx.x*256 + threadIdx.x;
  const int total = NG + NG*3 + NN*3 + NG*3 + NN*3; // 60112
  if (i >= total) return;
  float v;
  if (i < 16){
    v = e0g[i] + Etg[i] + Etg[16+i];
  } else if (i < 64){
    int j = i - 16; int g = j/3, t = j - g*3;
    v = (t == 0) ? e0g[g] : Etg[(t-1)*16 + g];
  } else if (i < 64 + NN*3){
    v = -gpos[i-64];
  } else if (i < 64 + NN*3 + 48){
    v = td[i - (64 + NN*3)];
  } else {
    v = adp[i - (64 + NN*3 + 48)];
  }
  if (flag[0]) ((__hip_bfloat16*)outv)[i] = __float2bfloat16(v);
  else         ((float*)outv)[i] = v;
}

extern "C" void kernel_launch(void* const* d_in, const int* in_sizes, int n_in,
                              void* d_out, int out_size, void* d_ws, size_t ws_size,
                              hipStream_t stream) {
  if (ws_size < WS2_FLOATS*sizeof(float)) return;
  const bool have_efd = (ws_size >= WS3_FLOATS*sizeof(float));
  const int* ei    = (const int*)d_in[14];
  const int* batch = (const int*)d_in[15];
  float* ws = (float*)d_ws;
  int* flag = (int*)(ws + O_FLAG);
  float* EFD = have_efd ? (ws + O_EFD) : nullptr;

  hipMemsetAsync(ws + OFF_ACC, 0, ACC_FLOATS*sizeof(float), stream);
  k_detect<<<1, 256, 0, stream>>>((const unsigned*)d_in[1], flag);
  k_load_all<<<(LD_TOTAL+255)/256, 256, 0, stream>>>(
      d_in[0], d_in[1], d_in[2], d_in[3], d_in[4], d_in[5], d_in[6], d_in[7],
      d_in[8], d_in[9], d_in[10], d_in[11], d_in[12], d_in[13], ws, flag);
  k_transpose_all<<<320, 256, 0, stream>>>(ws);

  k_geom<<<(NE+255)/256, 256, 0, stream>>>(ws+OFF_PIN, ws+OFF_SHF, ei,
                                           ws+OFF_SH, ws+OFF_EF, ws+OFF_RL, ws+OFF_UV, EFD);
  k_init_nodes<<<(NN+3)/4, 256, 0, stream>>>(ws+OFF_ATT, ws+O_WEMB, ws+O_AE, batch, ws+OFF_NF0, ws+O_E0G);

  float* WBUF = ws + O_WBUF;
  int* offr  = (int*)(ws + O_OFFR);
  int* offs_ = (int*)(ws + O_OFFS);
  int* curr  = (int*)(ws + O_CURR);
  int* curs  = (int*)(ws + O_CURS);
  int* listr = (int*)(ws + O_LISTR);
  int* lists = (int*)(ws + O_LISTS);
  hipMemsetAsync(curr, 0, 2*NN*sizeof(int), stream);
  k_csr_count<<<(NE+255)/256, 256, 0, stream>>>(ei, curr, curs);
  k_csr_scan<<<1, 256, 0, stream>>>(curr, curs, offr, offs_);
  k_csr_fill<<<(NE+255)/256, 256, 0, stream>>>(ei, curr, curs, listr, lists);

  const size_t NF[3]  = {OFF_NF0, OFF_NF1, OFF_NF2};
  const size_t MSG[2] = {OFF_MSG0, OFF_MSG1};
  dim3 ling(120, 9);
  float* GA = ws + OFF_NF2;
  float* GB = ws + OFF_MSG1;

  // ---------- forward ----------
  for (int t = 0; t < NT; ++t){
    k_radial<<<1024, 256, 0, stream>>>(ws+OFF_EF, ws+O_R1 + (size_t)t*512, ws+O_R2 + (size_t)t*4096, WBUF);
    k_agg<<<640, 256, 0, stream>>>(WBUF, ws+OFF_SH, ws+NF[t], ei, offr, listr, ws+OFF_AGG);
    k_lin2<<<ling, 256, 0, stream>>>(ws+OFF_AGG, ws+O_WMIX + (size_t)t*12288, nullptr, ws+MSG[t], 0);
    k_lin2<<<ling, 256, 0, stream>>>(ws+NF[t],   ws+O_WSC  + (size_t)t*12288, nullptr, ws+NF[t+1], 0);
    k_lin2<<<ling, 256, 0, stream>>>(ws+MSG[t],  ws+O_WPROD+ (size_t)t*12288, ws+O_WPOLY + (size_t)t*192,
                                     ws+NF[t+1], 3);  // poly-gated + accumulate
    k_edip<<<(NN+3)/4, 256, 0, stream>>>(ws+NF[t+1], ws+O_WE + (size_t)t*64, ws+O_WD + (size_t)t*64,
                                         batch, ws+O_ETG + (size_t)t*16, ws+O_ADP, ws+O_TD);
  }

  // ---------- backward ----------
  k_init_gnf<<<(NN*576+255)/256, 256, 0, stream>>>(GA, ws+O_WE + 64);
  { // t = 1 (WBUF holds w1 from fwd)
    int t = 1;
    k_lin2<<<ling, 256, 0, stream>>>(GA, ws+O_WPRODT + (size_t)t*12288, nullptr, ws+OFF_AGG, 0);
    k_poly_bwd<<<(NN+3)/4, 256, 0, stream>>>(ws+OFF_AGG, ws+MSG[t], ws+O_WPOLY + (size_t)t*192);
    k_lin2<<<ling, 256, 0, stream>>>(GA, ws+O_WSCT + (size_t)t*12288, nullptr, GB, 0);
    k_lin2<<<ling, 256, 0, stream>>>(ws+OFF_AGG, ws+O_WMIXT + (size_t)t*12288, nullptr, GA, 0);
    k_edge_bwd3<<<1024, 256, 0, stream>>>(ws+OFF_EF, EFD, ws+OFF_SH, ws+OFF_RL, ws+OFF_UV,
                                          ws+NF[t], GA, ei,
                                          ws+O_R1 + (size_t)t*512, ws+O_R2T + (size_t)t*4096,
                                          offr, listr, WBUF, ws+O_GVEC, 1, 0);
    k_ghgather<<<640, 256, 0, stream>>>(WBUF, offs_, lists, GB);
    k_add_we<<<(NN*64+255)/256, 256, 0, stream>>>(GB, ws+O_WE);
  }
  { // t = 0 (recompute w0)
    int t = 0;
    k_radial<<<1024, 256, 0, stream>>>(ws+OFF_EF, ws+O_R1, ws+O_R2, WBUF);
    k_lin2<<<ling, 256, 0, stream>>>(GB, ws+O_WPRODT + (size_t)t*12288, nullptr, ws+OFF_AGG, 0);
    k_poly_bwd<<<(NN+3)/4, 256, 0, stream>>>(ws+OFF_AGG, ws+MSG[t], ws+O_WPOLY + (size_t)t*192);
    k_lin2<<<ling, 256, 0, stream>>>(ws+OFF_AGG, ws+O_WMIXT + (size_t)t*12288, nullptr, GA, 0);
    k_edge_bwd3<<<1024, 256, 0, stream>>>(ws+OFF_EF, EFD, ws+OFF_SH, ws+OFF_RL, ws+OFF_UV,
                                          ws+NF[t], GA, ei,
                                          ws+O_R1, ws+O_R2T,
                                          offr, listr, WBUF, ws+O_GVEC, 0, 1);
  }

  k_gpos<<<(NN+255)/256, 256, 0, stream>>>(ws+O_GVEC, offr, listr, offs_, lists, ws+O_GPOS);
  k_charge<<<(NN+255)/256, 256, 0, stream>>>(ws+OFF_CHG, ws+OFF_PIN, batch, ws+O_TD);
  k_writeout<<<(60112+255)/256, 256, 0, stream>>>(ws+O_E0G, ws+O_ETG, ws+O_TD, ws+O_ADP, ws+O_GPOS, d_out, flag);
}

// Round 6
// 1045.881 us; speedup vs baseline: 3.1415x; 1.8755x over previous
//
#include <hip/hip_runtime.h>
#include <hip/hip_bf16.h>

#define NN 10000
#define NE 160000
#define NZ 10
#define NC 64
#define NBES 8
#define NG 16
#define NT 2

static constexpr float PI_F  = 3.14159265358979323846f;
static constexpr float KBES  = 0.63245553203367587f;  // sqrt(2/5)
static constexpr float S3    = 1.73205080756887729f;
static constexpr float S5    = 2.23606797749978969f;
static constexpr float S15   = 3.87298334620741688f;

// ---- workspace layout (float offsets) ----
static constexpr size_t OFF_SH   = 0;
static constexpr size_t OFF_EF   = OFF_SH  + (size_t)NE*9;
static constexpr size_t OFF_RL   = OFF_EF  + (size_t)NE*8;
static constexpr size_t OFF_UV   = OFF_RL  + (size_t)NE;
static constexpr size_t OFF_PIN  = OFF_UV  + (size_t)NE*3;
static constexpr size_t OFF_ATT  = OFF_PIN + (size_t)NN*3;
static constexpr size_t OFF_CHG  = OFF_ATT + (size_t)NN*NZ;
static constexpr size_t OFF_SHF  = OFF_CHG + (size_t)NN;
static constexpr size_t NFSZ     = (size_t)NN*576;
static constexpr size_t OFF_NF0  = OFF_SHF + (size_t)NE*3;
static constexpr size_t OFF_NF1  = OFF_NF0 + NFSZ;
static constexpr size_t OFF_NF2  = OFF_NF1 + NFSZ;
static constexpr size_t OFF_MSG0 = OFF_NF2 + NFSZ;
static constexpr size_t OFF_MSG1 = OFF_MSG0+ NFSZ;
static constexpr size_t OFF_AGG  = OFF_MSG1+ NFSZ;   // fwd agg scratch; bwd compact GA0/GB0
static constexpr size_t OFF_W    = OFF_AGG + NFSZ;
static constexpr size_t O_WEMB   = OFF_W;
static constexpr size_t O_AE     = O_WEMB + 640;
static constexpr size_t O_R1     = O_AE   + 16;
static constexpr size_t O_R2     = O_R1   + 1024;
static constexpr size_t O_R2T    = O_R2   + 8192;
static constexpr size_t O_WMIX   = O_R2T  + 8192;
static constexpr size_t O_WMIXT  = O_WMIX + 24576;
static constexpr size_t O_WSC    = O_WMIXT+ 24576;
static constexpr size_t O_WSCT   = O_WSC  + 24576;
static constexpr size_t O_WPROD  = O_WSCT + 24576;
static constexpr size_t O_WPRODT = O_WPROD+ 24576;
static constexpr size_t O_WPOLY  = O_WPRODT+24576;
static constexpr size_t O_WE     = O_WPOLY+ 384;
static constexpr size_t O_WD     = O_WE   + 128;
static constexpr size_t OFF_ACC  = O_WD   + 128;
static constexpr size_t O_E0G    = OFF_ACC;
static constexpr size_t O_ETG    = O_E0G + 16;
static constexpr size_t O_TD     = O_ETG + 32;
static constexpr size_t O_ADP    = O_TD  + 48;
static constexpr size_t O_GPOS   = O_ADP + (size_t)NN*3;
// per-node energy staging ALIASES gpos (k_reduce runs before k_gpos)
static constexpr size_t O_EN0    = O_GPOS;
static constexpr size_t O_EN1    = O_GPOS + NN;
static constexpr size_t O_E0N    = O_GPOS + 2*NN;
static constexpr size_t O_GVEC   = O_GPOS+ (size_t)NN*3;     // per-edge dE/dvec (NOT zeroed)
static constexpr size_t ACC_FLOATS = O_GVEC - OFF_ACC;
static constexpr size_t O_FLAG   = O_GVEC + (size_t)NE*3;
static constexpr size_t O_GVP    = O_FLAG + 4;               // const grad vectors (64 each)
static constexpr size_t O_GNFC   = O_GVP + 64;
static constexpr size_t WS1_FLOATS = O_GNFC + 64;
static constexpr size_t O_WBUF  = WS1_FLOATS;                // E*64 radial weights / gh staging
static constexpr size_t O_OFFR  = O_WBUF + (size_t)NE*64;    // ints from here
static constexpr size_t O_OFFS  = O_OFFR + (NN+1);
static constexpr size_t O_CURR  = O_OFFS + (NN+1);
static constexpr size_t O_CURS  = O_CURR + NN;
static constexpr size_t O_LISTR = O_CURS + NN;
static constexpr size_t O_LISTS = O_LISTR + (size_t)NE;
static constexpr size_t WS2_FLOATS = O_LISTS + (size_t)NE;   // mandatory (~201 MB)
static constexpr size_t O_EFD   = WS2_FLOATS;                // optional derivative table
static constexpr size_t WS3_FLOATS = O_EFD + (size_t)NE*8;

__device__ __forceinline__ float rlane(float v, int l){
  return __int_as_float(__builtin_amdgcn_readlane(__float_as_int(v), l));
}

__device__ __forceinline__ void edge_defdr(float L, float* dd){
  float ur = L*0.2f;
  if (ur < 1.f){
    float u2=ur*ur, u4=u2*u2, u5=u4*ur;
    float fc = 1.f - 21.f*u5 + 35.f*u5*ur - 15.f*u5*u2;
    float omu = 1.f - ur;
    float dfc = -105.f*u4*omu*omu;
    float invr = 1.f/(L + 1e-9f);
    #pragma unroll
    for (int b = 0; b < 8; ++b){
      float nb = (float)(b+1);
      float arg = nb*PI_F*ur;
      float sn = sinf(arg), cs = cosf(arg);
      float bes = KBES*sn*invr;
      float dbes = KBES*(nb*PI_F*0.2f)*cs*invr - bes*invr;
      dd[b] = dbes*fc + bes*dfc*0.2f;
    }
  } else {
    #pragma unroll
    for (int b = 0; b < 8; ++b) dd[b] = 0.f;
  }
}

// ---------- dtype detection ----------
__global__ void k_detect(const unsigned* __restrict__ raw, int* __restrict__ flag){
  __shared__ int found;
  if (threadIdx.x == 0) found = 0;
  __syncthreads();
  for (int i = threadIdx.x; i < 4096; i += 256){
    unsigned w = raw[i];
    if (w == 0x00003F80u || w == 0x3F803F80u) found = 1;
  }
  __syncthreads();
  if (threadIdx.x == 0) flag[0] = found;
}

// ---------- fused loader ----------
static constexpr int LD_CNT[14] = {NN*3, NN*NZ, NN, NE*3, NZ*64, NZ, NT*NBES*64, NT*64*64,
                                   NT*3*64*64, NT*3*64*64, NT*64*3, NT*3*64*64, NT*64, NT*64};
static constexpr int LD_TOTAL = NN*3 + NN*NZ + NN + NE*3 + NZ*64 + NZ + NT*NBES*64 + NT*64*64
                              + 3*(NT*3*64*64) + NT*64*3 + 4*(NT*64) - NT*64*2;
__global__ __launch_bounds__(256) void k_load_all(
    const void* s0, const void* s1, const void* s2, const void* s3, const void* s4,
    const void* s5, const void* s6, const void* s7, const void* s8, const void* s9,
    const void* s10, const void* s11, const void* s12, const void* s13,
    float* __restrict__ ws, const int* __restrict__ flag){
  const void* srcs[14] = {s0,s1,s2,s3,s4,s5,s6,s7,s8,s9,s10,s11,s12,s13};
  const size_t dsts[14] = {OFF_PIN, OFF_ATT, OFF_CHG, OFF_SHF, O_WEMB, O_AE, O_R1, O_R2,
                           O_WMIX, O_WSC, O_WPOLY, O_WPROD, O_WE, O_WD};
  int i = blockIdx.x*256 + threadIdx.x;
  int seg = -1, off = i;
  #pragma unroll
  for (int j = 0; j < 14; ++j){
    if (seg < 0){
      if (off < LD_CNT[j]) seg = j;
      else off -= LD_CNT[j];
    }
  }
  if (seg < 0) return;
  float v = flag[0] ? __bfloat162float(((const __hip_bfloat16*)srcs[seg])[off])
                    : ((const float*)srcs[seg])[off];
  ws[dsts[seg] + off] = v;
}

// ---------- fused transposes ----------
__global__ void k_transpose_all(float* __restrict__ ws){
  const size_t srcs[4] = {O_R2, O_WMIX, O_WSC, O_WPROD};
  const size_t dsts[4] = {O_R2T, O_WMIXT, O_WSCT, O_WPRODT};
  const int cnts[4] = {2, 6, 6, 6};
  int i = blockIdx.x*256 + threadIdx.x;
  if (i >= 20*4096) return;
  int mm = i >> 12, r = (i >> 6) & 63, c = i & 63;
  int grp = 0, m = mm;
  #pragma unroll
  for (int j = 0; j < 4; ++j){ if (m >= cnts[j] && j < 3){ m -= cnts[j]; grp = j+1; } }
  ws[dsts[grp] + (size_t)m*4096 + (size_t)c*64 + r] =
      ws[srcs[grp] + (size_t)m*4096 + (size_t)r*64 + c];
}

// ---------- edge geometry ----------
__global__ void k_geom(const float* __restrict__ pos, const float* __restrict__ shifts,
                       const int* __restrict__ ei, float* __restrict__ sh, float* __restrict__ ef,
                       float* __restrict__ rl, float* __restrict__ uv, float* __restrict__ efd){
  int e = blockIdx.x*256 + threadIdx.x;
  if (e >= NE) return;
  int s = ei[e], r = ei[NE + e];
  float vx = pos[s*3+0] - pos[r*3+0] + shifts[(size_t)e*3+0];
  float vy = pos[s*3+1] - pos[r*3+1] + shifts[(size_t)e*3+1];
  float vz = pos[s*3+2] - pos[r*3+2] + shifts[(size_t)e*3+2];
  float L = sqrtf(vx*vx + vy*vy + vz*vz + 1e-12f);
  float inv = 1.f / L;
  float x = vx*inv, y = vy*inv, z = vz*inv;
  float* shp = sh + (size_t)e*9;
  shp[0] = 1.f;     shp[1] = S3*x;    shp[2] = S3*y;   shp[3] = S3*z;
  shp[4] = S15*x*y; shp[5] = S15*y*z; shp[6] = 0.5f*S5*(3.f*z*z - 1.f);
  shp[7] = S15*x*z; shp[8] = 0.5f*S15*(x*x - y*y);
  rl[e] = L;
  uv[(size_t)e*3+0] = x; uv[(size_t)e*3+1] = y; uv[(size_t)e*3+2] = z;
  float ur = L * 0.2f;
  float fc = 0.f;
  if (ur < 1.f){
    float u2 = ur*ur, u4 = u2*u2, u5 = u4*ur;
    fc = 1.f - 21.f*u5 + 35.f*u5*ur - 15.f*u5*u2;
  }
  float invr = 1.f / (L + 1e-9f);
  float* efp = ef + (size_t)e*8;
  #pragma unroll
  for (int b = 0; b < 8; ++b){
    float arg = (float)(b+1) * PI_F * ur;
    efp[b] = KBES * sinf(arg) * invr * fc;
  }
  if (efd){
    float dd[8];
    edge_defdr(L, dd);
    #pragma unroll
    for (int b = 0; b < 8; ++b) efd[(size_t)e*8+b] = dd[b];
  }
}

// ---------- node init (no atomics; per-node e0) ----------
__global__ __launch_bounds__(256) void k_init_nodes(
    const float* __restrict__ attrs, const float* __restrict__ Wemb,
    const float* __restrict__ ae, float* __restrict__ nf0, float* __restrict__ e0n){
  int lane = threadIdx.x & 63;
  int n = blockIdx.x*4 + (threadIdx.x >> 6);
  if (n >= NN) return;
  float acc = 0.f;
  #pragma unroll
  for (int z = 0; z < NZ; ++z) acc = fmaf(attrs[(size_t)n*NZ+z], Wemb[z*64+lane], acc);
  size_t base = (size_t)n*576;
  nf0[base + lane] = acc;
  #pragma unroll
  for (int k = 1; k < 4; ++k) nf0[base + (size_t)k*64 + lane] = 0.f;   // planes 4..8 never read
  if (lane == 0){
    float e = 0.f;
    #pragma unroll
    for (int z = 0; z < NZ; ++z) e = fmaf(attrs[(size_t)n*NZ+z], ae[z], e);
    e0n[n] = e;
  }
}

// ================= CSR construction =================
__global__ void k_csr_count(const int* __restrict__ ei, int* __restrict__ cntr, int* __restrict__ cnts){
  int e = blockIdx.x*256 + threadIdx.x;
  if (e >= NE) return;
  atomicAdd(&cntr[ei[NE+e]], 1);
  atomicAdd(&cnts[ei[e]], 1);
}

__global__ void k_csr_scan(int* __restrict__ cntr, int* __restrict__ cnts,
                           int* __restrict__ offr, int* __restrict__ offs_){
  __shared__ int part[256];
  for (int q = 0; q < 2; ++q){
    int* c   = q ? cnts  : cntr;
    int* off = q ? offs_ : offr;
    const int chunk = (NN + 255)/256;
    int lo = threadIdx.x*chunk, hi = lo+chunk; if (hi > NN) hi = NN; if (lo > NN) lo = NN;
    int s = 0;
    for (int i = lo; i < hi; ++i) s += c[i];
    part[threadIdx.x] = s;
    __syncthreads();
    for (int o = 1; o < 256; o <<= 1){
      int v = (threadIdx.x >= o) ? part[threadIdx.x-o] : 0;
      __syncthreads();
      part[threadIdx.x] += v;
      __syncthreads();
    }
    int run = (threadIdx.x == 0) ? 0 : part[threadIdx.x-1];
    for (int i = lo; i < hi; ++i){
      int ci = c[i];
      off[i] = run; c[i] = run;
      run += ci;
    }
    if (threadIdx.x == 255) off[NN] = run;
    __syncthreads();
  }
}

__global__ void k_csr_fill(const int* __restrict__ ei, int* __restrict__ curr, int* __restrict__ curs,
                           int* __restrict__ listr, int* __restrict__ lists){
  int e = blockIdx.x*256 + threadIdx.x;
  if (e >= NE) return;
  int pr = atomicAdd(&curr[ei[NE+e]], 1); listr[pr] = e;
  int ps = atomicAdd(&curs[ei[e]], 1);    lists[ps] = e;
}

// ================= radial MLP (VGPR-resident) =================
__global__ __launch_bounds__(256) void k_radial(
    const float* __restrict__ ef, const float* __restrict__ R1, const float* __restrict__ R2,
    float* __restrict__ wbuf){
  int lane = threadIdx.x & 63;
  int wid = blockIdx.x*4 + (threadIdx.x >> 6);
  int nw  = gridDim.x*4;
  float r1c[8], r2c[64];
  #pragma unroll
  for (int j = 0; j < 8; ++j)  r1c[j] = R1[j*64 + lane];
  #pragma unroll
  for (int j = 0; j < 64; ++j) r2c[j] = R2[j*64 + lane];
  for (int e = wid; e < NE; e += nw){
    float efv = ef[(size_t)e*8 + (lane & 7)];
    float a = 0.f;
    #pragma unroll
    for (int b = 0; b < 8; ++b) a = fmaf(rlane(efv, b), r1c[b], a);
    float sg = 1.f/(1.f + __expf(-a));
    float sl = a*sg;
    float w0 = 0.f, w1 = 0.f, w2 = 0.f, w3 = 0.f;
    #pragma unroll
    for (int j = 0; j < 64; j += 4){
      w0 = fmaf(rlane(sl, j  ), r2c[j  ], w0);
      w1 = fmaf(rlane(sl, j+1), r2c[j+1], w1);
      w2 = fmaf(rlane(sl, j+2), r2c[j+2], w2);
      w3 = fmaf(rlane(sl, j+3), r2c[j+3], w3);
    }
    wbuf[(size_t)e*64 + lane] = (w0+w1) + (w2+w3);
  }
}

// ================= aggregation via receiver CSR (planes 0..3 only) =================
__global__ __launch_bounds__(256) void k_agg(
    const float* __restrict__ wbuf, const float* __restrict__ sh, const float* __restrict__ nf,
    const int* __restrict__ ei, const int* __restrict__ offr, const int* __restrict__ listr,
    float* __restrict__ agg){
  int lane = threadIdx.x & 63;
  int wid = blockIdx.x*4 + (threadIdx.x >> 6);
  int nw  = gridDim.x*4;
  for (int n = wid; n < NN; n += nw){
    int lo = offr[n], hi = offr[n+1];
    float acc[4];
    #pragma unroll
    for (int k = 0; k < 4; ++k) acc[k] = 0.f;
    for (int i = lo; i < hi; ++i){
      int e = __builtin_amdgcn_readfirstlane(listr[i]);
      int s = __builtin_amdgcn_readfirstlane(ei[e]);
      float wh = wbuf[(size_t)e*64 + lane] * nf[(size_t)s*576 + lane];
      const float* shp = sh + (size_t)e*9;
      #pragma unroll
      for (int k = 0; k < 4; ++k) acc[k] = fmaf(wh, shp[k], acc[k]);
    }
    size_t ob = (size_t)n*576 + lane;
    #pragma unroll
    for (int k = 0; k < 4; ++k) agg[ob + (size_t)k*64] = acc[k]*(1.f/16.f);
  }
}

// ================= per-l linear, readlane matvec (launched with gridDim.y=4) =================
__global__ __launch_bounds__(256) void k_lin2(
    const float* __restrict__ in, const float* __restrict__ W3, const float* __restrict__ wp,
    float* __restrict__ out, int flags){
  int k = blockIdx.y;
  int l = (k==0) ? 0 : ((k<4) ? 1 : 2);
  const float* W = W3 + (size_t)l*4096;
  int lane = threadIdx.x & 63;
  float wcol[64];
  #pragma unroll
  for (int j = 0; j < 64; ++j) wcol[j] = W[j*64 + lane];
  float p0 = 0.f, p1 = 0.f, p2 = 0.f;
  if (flags & 2){ p0 = wp[lane*3]; p1 = wp[lane*3+1]; p2 = wp[lane*3+2]; }
  int wid = blockIdx.x*4 + (threadIdx.x >> 6);
  int nw  = gridDim.x*4;
  for (int n = wid; n < NN; n += nw){
    size_t base = (size_t)n*576;
    float x = in[base + (size_t)k*64 + lane];
    if (flags & 2){
      float s0 = in[base + lane];
      x *= fmaf(fmaf(p2, s0, p1), s0, p0);
    }
    float a0 = 0.f, a1 = 0.f, a2 = 0.f, a3 = 0.f;
    #pragma unroll
    for (int j = 0; j < 64; j += 4){
      a0 = fmaf(rlane(x, j  ), wcol[j  ], a0);
      a1 = fmaf(rlane(x, j+1), wcol[j+1], a1);
      a2 = fmaf(rlane(x, j+2), wcol[j+2], a2);
      a3 = fmaf(rlane(x, j+3), wcol[j+3], a3);
    }
    float acc = (a0+a1) + (a2+a3);
    float* o = out + base + (size_t)k*64 + lane;
    if (flags & 1) *o += acc; else *o = acc;
  }
}

// ================= compact 64-wide matvec: out[n,d] = sum_c in[n,c] W[c,d] =================
__global__ __launch_bounds__(256) void k_lin0(
    const float* __restrict__ in, const float* __restrict__ W, float* __restrict__ out){
  int lane = threadIdx.x & 63;
  float wcol[64];
  #pragma unroll
  for (int j = 0; j < 64; ++j) wcol[j] = W[j*64 + lane];
  int wid = blockIdx.x*4 + (threadIdx.x >> 6);
  int nw  = gridDim.x*4;
  for (int n = wid; n < NN; n += nw){
    float x = in[(size_t)n*64 + lane];
    float a0 = 0.f, a1 = 0.f, a2 = 0.f, a3 = 0.f;
    #pragma unroll
    for (int j = 0; j < 64; j += 4){
      a0 = fmaf(rlane(x, j  ), wcol[j  ], a0);
      a1 = fmaf(rlane(x, j+1), wcol[j+1], a1);
      a2 = fmaf(rlane(x, j+2), wcol[j+2], a2);
      a3 = fmaf(rlane(x, j+3), wcol[j+3], a3);
    }
    out[(size_t)n*64 + lane] = (a0+a1) + (a2+a3);
  }
}

// ================= energies & dipoles: per-node staging, NO atomics =================
__global__ __launch_bounds__(256) void k_edip(
    const float* __restrict__ nf, const float* __restrict__ we,
    const float* __restrict__ wd, float* __restrict__ en, float* __restrict__ adp){
  int lane = threadIdx.x & 63;
  int n = blockIdx.x*4 + (threadIdx.x >> 6);
  if (n >= NN) return;
  float v = nf[(size_t)n*576 + lane]*we[lane];
  #pragma unroll
  for (int o = 32; o; o >>= 1) v += __shfl_xor(v, o, 64);
  if (lane == 0) en[n] = v;
  #pragma unroll
  for (int j = 0; j < 3; ++j){
    float dv = nf[(size_t)n*576 + (size_t)(j+1)*64 + lane]*wd[lane];
    #pragma unroll
    for (int o = 32; o; o >>= 1) dv += __shfl_xor(dv, o, 64);
    if (lane == 0) adp[n*3+j] += dv;
  }
}

// ================= segmented final reduction (batch sorted) =================
__global__ void k_reduce(const float* __restrict__ e0n, const float* __restrict__ en0,
                         const float* __restrict__ en1, const float* __restrict__ adp,
                         const float* __restrict__ q, const float* __restrict__ pos,
                         const int* __restrict__ batch, float* __restrict__ e0g,
                         float* __restrict__ Etg, float* __restrict__ td){
  int n = blockIdx.x*256 + threadIdx.x;
  int lane = threadIdx.x & 63;
  bool valid = (n < NN);
  int g = valid ? batch[n] : -1;
  float v0=0.f, v1=0.f, v2=0.f, tx=0.f, ty=0.f, tz=0.f;
  if (valid){
    v0 = e0n[n]; v1 = en0[n]; v2 = en1[n];
    float qq = q[n];
    tx = adp[n*3+0] + qq*pos[n*3+0];
    ty = adp[n*3+1] + qq*pos[n*3+1];
    tz = adp[n*3+2] + qq*pos[n*3+2];
  }
  int g0 = __shfl(g, 0, 64), g63 = __shfl(g, 63, 64);
  if (g0 == g63 && g0 >= 0){
    #pragma unroll
    for (int o = 32; o; o >>= 1){
      v0 += __shfl_xor(v0, o, 64); v1 += __shfl_xor(v1, o, 64); v2 += __shfl_xor(v2, o, 64);
      tx += __shfl_xor(tx, o, 64); ty += __shfl_xor(ty, o, 64); tz += __shfl_xor(tz, o, 64);
    }
    if (lane == 0){
      atomicAdd(&e0g[g0], v0); atomicAdd(&Etg[g0], v1); atomicAdd(&Etg[16+g0], v2);
      atomicAdd(&td[g0*3+0], tx); atomicAdd(&td[g0*3+1], ty); atomicAdd(&td[g0*3+2], tz);
    }
  } else if (valid){
    atomicAdd(&e0g[g], v0); atomicAdd(&Etg[g], v1); atomicAdd(&Etg[16+g], v2);
    atomicAdd(&td[g*3+0], tx); atomicAdd(&td[g*3+1], ty); atomicAdd(&td[g*3+2], tz);
  }
}

// ================= backward head: constant k=0 gradient vectors =================
__global__ void k_bwd_head(const float* __restrict__ WPRODT1, const float* __restrict__ WSCT1,
                           const float* __restrict__ we1, const float* __restrict__ we0,
                           float* __restrict__ gvp, float* __restrict__ gnfc){
  int d = threadIdx.x;  // 64 threads
  float a = 0.f, b = 0.f;
  #pragma unroll
  for (int c = 0; c < 64; ++c){
    float w = we1[c];
    a = fmaf(w, WPRODT1[c*64+d], a);
    b = fmaf(w, WSCT1[c*64+d], b);
  }
  gvp[d] = a;
  gnfc[d] = b + we0[d];
}

// ================= poly backward, k=0 plane only =================
__global__ __launch_bounds__(256) void k_polybwd0(
    const float* __restrict__ gmp, int per_node, const float* __restrict__ msgbase,
    const float* __restrict__ wp, float* __restrict__ out){
  int lane = threadIdx.x & 63;
  int n = blockIdx.x*4 + (threadIdx.x >> 6);
  if (n >= NN) return;
  float g = per_node ? gmp[(size_t)n*64 + lane] : gmp[lane];
  float s0 = msgbase[(size_t)n*576 + lane];
  float p0 = wp[lane*3], p1 = wp[lane*3+1], p2 = wp[lane*3+2];
  float poly = fmaf(fmaf(p2, s0, p1), s0, p0);
  float dp   = fmaf(2.f*p2, s0, p1);
  out[(size_t)n*64 + lane] = g*fmaf(s0, dp, poly);
}

// ================= per-receiver k=0 backward edge kernel =================
__global__ __launch_bounds__(256) void k_edge_bwd_s(
    const float* __restrict__ ef, const float* __restrict__ efd,
    const float* __restrict__ rl, const float* __restrict__ uv,
    const float* __restrict__ nf, const float* __restrict__ gagg0, const int* __restrict__ ei,
    const float* __restrict__ R1, const float* __restrict__ R2T,
    const int* __restrict__ offr, const int* __restrict__ listr,
    float* __restrict__ wbuf, float* __restrict__ gvec, int need_gh, int accum){
  int lane = threadIdx.x & 63;
  int wid = blockIdx.x*4 + (threadIdx.x >> 6);
  int nw  = gridDim.x*4;
  float r1c[8], r2tc[64];
  #pragma unroll
  for (int j = 0; j < 8; ++j)  r1c[j]  = R1[j*64 + lane];
  #pragma unroll
  for (int j = 0; j < 64; ++j) r2tc[j] = R2T[j*64 + lane];
  for (int n = wid; n < NN; n += nw){
    float gm = gagg0[(size_t)n*64 + lane]*(1.f/16.f);   // per-channel, S = gm (sh0 = 1)
    int lo = offr[n], hi = offr[n+1];
    for (int i = lo; i < hi; ++i){
      int e = __builtin_amdgcn_readfirstlane(listr[i]);
      int s = __builtin_amdgcn_readfirstlane(ei[e]);
      float h = nf[(size_t)s*576 + lane];
      float gw = h*gm;
      // radial MLP backward
      float g0 = 0.f, g1 = 0.f, g2 = 0.f, g3 = 0.f;
      #pragma unroll
      for (int j = 0; j < 64; j += 4){
        g0 = fmaf(rlane(gw, j  ), r2tc[j  ], g0);
        g1 = fmaf(rlane(gw, j+1), r2tc[j+1], g1);
        g2 = fmaf(rlane(gw, j+2), r2tc[j+2], g2);
        g3 = fmaf(rlane(gw, j+3), r2tc[j+3], g3);
      }
      float gsl = (g0+g1) + (g2+g3);
      float efv = ef[(size_t)e*8 + (lane & 7)];
      float a = 0.f;
      #pragma unroll
      for (int b = 0; b < 8; ++b) a = fmaf(rlane(efv, b), r1c[b], a);
      float sg = 1.f/(1.f + __expf(-a));
      float ga = gsl * sg * fmaf(a, 1.f - sg, 1.f);
      float dd[8];
      if (efd){
        #pragma unroll
        for (int b = 0; b < 8; ++b) dd[b] = efd[(size_t)e*8 + b];
      } else {
        edge_defdr(rl[e], dd);
      }
      float t = 0.f;
      #pragma unroll
      for (int b = 0; b < 8; ++b) t = fmaf(r1c[b], dd[b], t);
      float rr = ga*t;
      #pragma unroll
      for (int o = 32; o; o >>= 1) rr += __shfl_xor(rr, o, 64);
      if (lane < 3){
        float comp = rr*uv[(size_t)e*3 + lane];
        size_t gi = (size_t)e*3 + lane;
        if (accum) gvec[gi] += comp; else gvec[gi] = comp;
      }
      if (need_gh){
        float w = wbuf[(size_t)e*64 + lane];
        wbuf[(size_t)e*64 + lane] = w*gm;   // gh staging
      }
    }
  }
}

// ================= gh gather (sender CSR) + const part -> compact gnf =================
__global__ __launch_bounds__(256) void k_ghgather0(
    const float* __restrict__ ghc, const int* __restrict__ offs_, const int* __restrict__ lists,
    const float* __restrict__ gnfc, float* __restrict__ out){
  int lane = threadIdx.x & 63;
  int wid = blockIdx.x*4 + (threadIdx.x >> 6);
  int nw  = gridDim.x*4;
  for (int n = wid; n < NN; n += nw){
    int lo = offs_[n], hi = offs_[n+1];
    float acc = gnfc[lane];
    for (int i = lo; i < hi; ++i){
      int e = __builtin_amdgcn_readfirstlane(lists[i]);
      acc += ghc[(size_t)e*64 + lane];
    }
    out[(size_t)n*64 + lane] = acc;
  }
}

// ---------- CSR-based force assembly ----------
__global__ void k_gpos(const float* __restrict__ gvec,
                       const int* __restrict__ offr, const int* __restrict__ listr,
                       const int* __restrict__ offs_, const int* __restrict__ lists,
                       float* __restrict__ gpos){
  int n = blockIdx.x*256 + threadIdx.x;
  if (n >= NN) return;
  float ax = 0.f, ay = 0.f, az = 0.f;
  for (int i = offs_[n]; i < offs_[n+1]; ++i){
    int e = lists[i];
    ax += gvec[(size_t)e*3]; ay += gvec[(size_t)e*3+1]; az += gvec[(size_t)e*3+2];
  }
  for (int i = offr[n]; i < offr[n+1]; ++i){
    int e = listr[i];
    ax -= gvec[(size_t)e*3]; ay -= gvec[(size_t)e*3+1]; az -= gvec[(size_t)e*3+2];
  }
  gpos[n*3+0] = ax; gpos[n*3+1] = ay; gpos[n*3+2] = az;
}

__global__ void k_writeout(const float* __restrict__ e0g, const float* __restrict__ Etg,
                           const float* __restrict__ td, const float* __restrict__ adp,
                           const float* __restrict__ gpos, void* __restrict__ outv,
                           const int* __restrict__ flag){
  int i = blockIdx.x*256 + threadIdx.x;
  const int total = NG + NG*3 + NN*3 + NG*3 + NN*3; // 60112
  if (i >= total) return;
  float v;
  if (i < 16){
    v = e0g[i] + Etg[i] + Etg[16+i];
  } else if (i < 64){
    int j = i - 16; int g = j/3, t = j - g*3;
    v = (t == 0) ? e0g[g] : Etg[(t-1)*16 + g];
  } else if (i < 64 + NN*3){
    v = -gpos[i-64];
  } else if (i < 64 + NN*3 + 48){
    v = td[i - (64 + NN*3)];
  } else {
    v = adp[i - (64 + NN*3 + 48)];
  }
  if (flag[0]) ((__hip_bfloat16*)outv)[i] = __float2bfloat16(v);
  else         ((float*)outv)[i] = v;
}

extern "C" void kernel_launch(void* const* d_in, const int* in_sizes, int n_in,
                              void* d_out, int out_size, void* d_ws, size_t ws_size,
                              hipStream_t stream) {
  if (ws_size < WS2_FLOATS*sizeof(float)) return;
  const bool have_efd = (ws_size >= WS3_FLOATS*sizeof(float));
  const int* ei    = (const int*)d_in[14];
  const int* batch = (const int*)d_in[15];
  float* ws = (float*)d_ws;
  int* flag = (int*)(ws + O_FLAG);
  float* EFD = have_efd ? (ws + O_EFD) : nullptr;

  hipMemsetAsync(ws + OFF_ACC, 0, ACC_FLOATS*sizeof(float), stream);
  k_detect<<<1, 256, 0, stream>>>((const unsigned*)d_in[1], flag);
  k_load_all<<<(LD_TOTAL+255)/256, 256, 0, stream>>>(
      d_in[0], d_in[1], d_in[2], d_in[3], d_in[4], d_in[5], d_in[6], d_in[7],
      d_in[8], d_in[9], d_in[10], d_in[11], d_in[12], d_in[13], ws, flag);
  k_transpose_all<<<320, 256, 0, stream>>>(ws);

  k_geom<<<(NE+255)/256, 256, 0, stream>>>(ws+OFF_PIN, ws+OFF_SHF, ei,
                                           ws+OFF_SH, ws+OFF_EF, ws+OFF_RL, ws+OFF_UV, EFD);
  k_init_nodes<<<(NN+3)/4, 256, 0, stream>>>(ws+OFF_ATT, ws+O_WEMB, ws+O_AE, ws+OFF_NF0, ws+O_E0N);

  float* WBUF = ws + O_WBUF;
  int* offr  = (int*)(ws + O_OFFR);
  int* offs_ = (int*)(ws + O_OFFS);
  int* curr  = (int*)(ws + O_CURR);
  int* curs  = (int*)(ws + O_CURS);
  int* listr = (int*)(ws + O_LISTR);
  int* lists = (int*)(ws + O_LISTS);
  hipMemsetAsync(curr, 0, 2*NN*sizeof(int), stream);
  k_csr_count<<<(NE+255)/256, 256, 0, stream>>>(ei, curr, curs);
  k_csr_scan<<<1, 256, 0, stream>>>(curr, curs, offr, offs_);
  k_csr_fill<<<(NE+255)/256, 256, 0, stream>>>(ei, curr, curs, listr, lists);

  const size_t NF[3]  = {OFF_NF0, OFF_NF1, OFF_NF2};
  const size_t MSG[2] = {OFF_MSG0, OFF_MSG1};
  dim3 ling(120, 4);          // planes 4..8 never influence outputs
  float* GA0 = ws + OFF_AGG;              // compact NN*64 (AGG free after forward)
  float* GB0 = ws + OFF_AGG + (size_t)NN*64;

  // ---------- forward ----------
  for (int t = 0; t < NT; ++t){
    k_radial<<<1024, 256, 0, stream>>>(ws+OFF_EF, ws+O_R1 + (size_t)t*512, ws+O_R2 + (size_t)t*4096, WBUF);
    k_agg<<<640, 256, 0, stream>>>(WBUF, ws+OFF_SH, ws+NF[t], ei, offr, listr, ws+OFF_AGG);
    k_lin2<<<ling, 256, 0, stream>>>(ws+OFF_AGG, ws+O_WMIX + (size_t)t*12288, nullptr, ws+MSG[t], 0);
    k_lin2<<<ling, 256, 0, stream>>>(ws+NF[t],   ws+O_WSC  + (size_t)t*12288, nullptr, ws+NF[t+1], 0);
    k_lin2<<<ling, 256, 0, stream>>>(ws+MSG[t],  ws+O_WPROD+ (size_t)t*12288, ws+O_WPOLY + (size_t)t*192,
                                     ws+NF[t+1], 3);
    k_edip<<<(NN+3)/4, 256, 0, stream>>>(ws+NF[t+1], ws+O_WE + (size_t)t*64, ws+O_WD + (size_t)t*64,
                                         ws + (t ? O_EN1 : O_EN0), ws+O_ADP);
  }

  // ---------- backward (k=0 plane only — k>0 grads are identically zero) ----------
  k_bwd_head<<<1, 64, 0, stream>>>(ws+O_WPRODT+12288, ws+O_WSCT+12288, ws+O_WE+64, ws+O_WE,
                                   ws+O_GVP, ws+O_GNFC);
  { // t = 1 (WBUF holds w1 from forward)
    k_polybwd0<<<(NN+3)/4, 256, 0, stream>>>(ws+O_GVP, 0, ws+MSG[1], ws+O_WPOLY+192, GB0);
    k_lin0<<<640, 256, 0, stream>>>(GB0, ws+O_WMIXT+12288, GA0);
    k_edge_bwd_s<<<640, 256, 0, stream>>>(ws+OFF_EF, EFD, ws+OFF_RL, ws+OFF_UV,
                                          ws+NF[1], GA0, ei,
                                          ws+O_R1+512, ws+O_R2T+4096,
                                          offr, listr, WBUF, ws+O_GVEC, 1, 0);
    k_ghgather0<<<640, 256, 0, stream>>>(WBUF, offs_, lists, ws+O_GNFC, GB0);
  }
  { // t = 0 (no w needed: gh unused)
    k_lin0<<<640, 256, 0, stream>>>(GB0, ws+O_WPRODT, GA0);          // gmp0 per node
    k_polybwd0<<<(NN+3)/4, 256, 0, stream>>>(GA0, 1, ws+MSG[0], ws+O_WPOLY, GB0);
    k_lin0<<<640, 256, 0, stream>>>(GB0, ws+O_WMIXT, GA0);           // gagg0
    k_edge_bwd_s<<<640, 256, 0, stream>>>(ws+OFF_EF, EFD, ws+OFF_RL, ws+OFF_UV,
                                          ws+NF[0], GA0, ei,
                                          ws+O_R1, ws+O_R2T,
                                          offr, listr, WBUF, ws+O_GVEC, 0, 1);
  }

  // reduce BEFORE gpos (per-node energy staging aliases the gpos slots)
  k_reduce<<<(NN+255)/256, 256, 0, stream>>>(ws+O_E0N, ws+O_EN0, ws+O_EN1, ws+O_ADP,
                                             ws+OFF_CHG, ws+OFF_PIN, batch,
                                             ws+O_E0G, ws+O_ETG, ws+O_TD);
  k_gpos<<<(NN+255)/256, 256, 0, stream>>>(ws+O_GVEC, offr, listr, offs_, lists, ws+O_GPOS);
  k_writeout<<<(60112+255)/256, 256, 0, stream>>>(ws+O_E0G, ws+O_ETG, ws+O_TD, ws+O_ADP, ws+O_GPOS, d_out, flag);
}